// Round 7
// baseline (463.238 us; speedup 1.0000x reference)
//
#include <hip/hip_runtime.h>
#include <stdint.h>

// ---- problem constants ----
#define NB 2
#define NL 1024
#define ND 2048
#define NE 4096
#define NN 16
#define NR 128
#define NKC 4
#define NBL (NB*NL)          // 2048 rows
#define EPSV 1e-5f
#define SEG_T 256            // scan L-split segment length (4 segments)
#define SCAN_T 64            // LDS chunk within a segment

typedef __attribute__((ext_vector_type(4))) float f32x4;
typedef __attribute__((ext_vector_type(8))) short short8;
typedef __attribute__((ext_vector_type(8))) unsigned short ushort8;
typedef __attribute__((ext_vector_type(4))) unsigned short ushort4_t;

__device__ __forceinline__ unsigned short f2bf(float f) {
  union { float f; unsigned u; } v; v.f = f;
  unsigned r = v.u + 0x7FFFu + ((v.u >> 16) & 1u);   // RNE
  return (unsigned short)(r >> 16);
}

__device__ __forceinline__ float bf2f(unsigned short u) {
  union { unsigned u; float f; } v; v.u = (unsigned)u << 16; return v.f;
}

__device__ __forceinline__ void load_lds16(const void* g, void* l) {
  __builtin_amdgcn_global_load_lds((const __attribute__((address_space(1))) void*)g,
                                   (__attribute__((address_space(3))) void*)l,
                                   16, 0, 0);
}

template<int CTRL>
__device__ __forceinline__ float dpp_mov(float v) {
  return __int_as_float(__builtin_amdgcn_update_dpp(
      0, __float_as_int(v), CTRL, 0xF, 0xF, true));
}

// ---------------- RMSNorm: resid[row,0:2048] -> rn_bf16 ----------------
__global__ void rmsnorm_kernel(const float* __restrict__ resid,
                               const float* __restrict__ nw,
                               unsigned short* __restrict__ rn) {
  int row = blockIdx.x;
  int tid = threadIdx.x;                 // 256 threads, 8 f32 each
  const float* r = resid + (size_t)row * ND;
  f32x4 v0 = *(const f32x4*)(r + tid * 8);
  f32x4 v1 = *(const f32x4*)(r + tid * 8 + 4);
  float vals[8];
#pragma unroll
  for (int i = 0; i < 4; ++i) { vals[i] = v0[i]; vals[4 + i] = v1[i]; }
  float ss = 0.f;
#pragma unroll
  for (int i = 0; i < 8; ++i) ss += vals[i] * vals[i];
  for (int o = 32; o > 0; o >>= 1) ss += __shfl_down(ss, o);
  __shared__ float ps[4];
  if ((tid & 63) == 0) ps[tid >> 6] = ss;
  __syncthreads();
  float tot = ps[0] + ps[1] + ps[2] + ps[3];
  float scale = rsqrtf(tot / (float)ND + EPSV);
  ushort8 o8;
#pragma unroll
  for (int i = 0; i < 8; ++i) o8[i] = f2bf(vals[i] * scale * nw[tid * 8 + i]);
  *(ushort8*)(rn + (size_t)row * ND + tid * 8) = o8;
}

// ---------------- generic f32 -> bf16 cast (8 elems/thread) ----------------
__global__ void cast_bf16_kernel(const float* __restrict__ in,
                                 unsigned short* __restrict__ out, int n8) {
  int i = blockIdx.x * blockDim.x + threadIdx.x;
  if (i >= n8) return;
  f32x4 a = *(const f32x4*)(in + (size_t)i * 8);
  f32x4 b = *(const f32x4*)(in + (size_t)i * 8 + 4);
  ushort8 o;
#pragma unroll
  for (int j = 0; j < 4; ++j) { o[j] = f2bf(a[j]); o[4 + j] = f2bf(b[j]); }
  *(ushort8*)(out + (size_t)i * 8) = o;
}

// ---- build concatenated [256 x 4096] bf16 weight: rows 0-127 wd1, 128-143 wB, 144-159 wC, rest 0
__global__ void build_wcat_kernel(const float* __restrict__ wd1,
                                  const float* __restrict__ wB,
                                  const float* __restrict__ wC,
                                  unsigned short* __restrict__ out) {
  int i = blockIdx.x * blockDim.x + threadIdx.x;   // total 256*4096/8 = 131072
  if (i >= 256 * NE / 8) return;
  int col8 = i & (NE / 8 - 1);
  int row = i >> 9;
  const float* src = nullptr; int srow = 0;
  if (row < 128)      { src = wd1; srow = row; }
  else if (row < 144) { src = wB;  srow = row - 128; }
  else if (row < 160) { src = wC;  srow = row - 144; }
  ushort8 o;
  if (src) {
    f32x4 a = *(const f32x4*)(src + (size_t)srow * NE + col8 * 8);
    f32x4 b = *(const f32x4*)(src + (size_t)srow * NE + col8 * 8 + 4);
#pragma unroll
    for (int j = 0; j < 4; ++j) { o[j] = f2bf(a[j]); o[4 + j] = f2bf(b[j]); }
  } else {
#pragma unroll
    for (int j = 0; j < 8; ++j) o[j] = 0;
  }
  *(ushort8*)(out + (size_t)row * NE + col8 * 8) = o;
}

// ======== 256x256 multi-phase counted-vmcnt GEMM (fused skip+in proj) ========
__global__ __launch_bounds__(512, 2)
void gemm256_fused(const unsigned short* __restrict__ A,
                   const unsigned short* __restrict__ B,
                   float* __restrict__ Gout,
                   unsigned short* __restrict__ Xout) {
  const int K = 2048, NH = K / 32;   // 64 K-halves
  __shared__ unsigned short Asl[4][8192];   // [slot][r*32+c]  r<256, c<32
  __shared__ unsigned short Bsl[4][8192];
  int tid = threadIdx.x;
  int w = tid >> 6, lane = tid & 63;
  int wm = w >> 2, wn = w & 3;
  int lr = lane & 15, kg8 = (lane >> 4) * 8;
  int m0 = blockIdx.y * 256, n0 = blockIdx.x * 256;

  const unsigned short* ga = A + (size_t)(m0 + (tid >> 2)) * K + (tid & 3) * 8;
  const unsigned short* gb = B + (size_t)(n0 + (tid >> 2)) * K + (tid & 3) * 8;
  char* ldsA0 = (char*)&Asl[0][0] + w * 1024;
  char* ldsB0 = (char*)&Bsl[0][0] + w * 1024;

  auto stageA = [&](int h) {
    int slot = h & 3, k0 = h * 32;
    load_lds16(ga + k0, ldsA0 + slot * 16384);
    load_lds16(ga + k0 + (size_t)128 * K, ldsA0 + slot * 16384 + 8192);
  };
  auto stageB = [&](int h) {
    int slot = h & 3, k0 = h * 32;
    load_lds16(gb + k0, ldsB0 + slot * 16384);
    load_lds16(gb + k0 + (size_t)128 * K, ldsB0 + slot * 16384 + 8192);
  };

  f32x4 acc[8][4];
#pragma unroll
  for (int i = 0; i < 8; ++i)
#pragma unroll
    for (int j = 0; j < 4; ++j) acc[i][j] = (f32x4){0.f, 0.f, 0.f, 0.f};

  stageA(0); stageB(0); stageA(1); stageB(1); stageA(2); stageB(2);
  asm volatile("s_waitcnt vmcnt(8)" ::: "memory");
  __builtin_amdgcn_s_barrier();

  for (int h = 0; h < NH; ++h) {
    int slot = h & 3;
    const unsigned short* As_ = &Asl[slot][0];
    const unsigned short* Bs_ = &Bsl[slot][0];
    int arow = wm * 128 + lr;
    int brow = wn * 64 + lr;
    short8 a[8], b[4];
#pragma unroll
    for (int i = 0; i < 4; ++i)
      a[i] = *(const short8*)&As_[(arow + i * 16) * 32 + kg8];
#pragma unroll
    for (int j = 0; j < 4; ++j)
      b[j] = *(const short8*)&Bs_[(brow + j * 16) * 32 + kg8];
    if (h + 3 < NH) stageA(h + 3);
    __builtin_amdgcn_s_barrier();
    __builtin_amdgcn_s_setprio(1);
#pragma unroll
    for (int i = 0; i < 4; ++i)
#pragma unroll
      for (int j = 0; j < 4; ++j)
        acc[i][j] = __builtin_amdgcn_mfma_f32_16x16x32_bf16(a[i], b[j], acc[i][j], 0, 0, 0);
    __builtin_amdgcn_s_setprio(0);
    __builtin_amdgcn_s_barrier();
#pragma unroll
    for (int i = 0; i < 4; ++i)
      a[4 + i] = *(const short8*)&As_[(arow + (4 + i) * 16) * 32 + kg8];
    if (h + 3 < NH) stageB(h + 3);
    __builtin_amdgcn_s_barrier();
    __builtin_amdgcn_s_setprio(1);
#pragma unroll
    for (int i = 0; i < 4; ++i)
#pragma unroll
      for (int j = 0; j < 4; ++j)
        acc[4 + i][j] = __builtin_amdgcn_mfma_f32_16x16x32_bf16(a[4 + i], b[j], acc[4 + i][j], 0, 0, 0);
    __builtin_amdgcn_s_setprio(0);
    if (h < NH - 3)       { asm volatile("s_waitcnt vmcnt(8)" ::: "memory"); }
    else if (h == NH - 3) { asm volatile("s_waitcnt vmcnt(4)" ::: "memory"); }
    else if (h == NH - 2) { asm volatile("s_waitcnt vmcnt(0)" ::: "memory"); }
    __builtin_amdgcn_s_barrier();
  }

  int rbase = m0 + wm * 128 + (lane >> 4) * 4;
  int cbase = n0 + wn * 64 + (lane & 15);
  bool isg = (n0 < 4096);
#pragma unroll
  for (int mf = 0; mf < 8; ++mf) {
#pragma unroll
    for (int nf = 0; nf < 4; ++nf) {
      int col = cbase + nf * 16;
#pragma unroll
      for (int rr = 0; rr < 4; ++rr) {
        int row = rbase + mf * 16 + rr;
        float v = acc[mf][nf][rr];
        if (isg) Gout[(size_t)row * 4096 + col] = v / (1.f + __expf(-v));
        else     Xout[(size_t)row * 4096 + (col - 4096)] = f2bf(v);
      }
    }
  }
}

// ---------------- bf16 MFMA GEMM: C[M,N] = A[M,K] @ B[N,K]^T ----------------
// MODE 0: plain f32 store (split-K via blockIdx.z); MODE 1: softplus->bf16;
// MODE 2: acc + add (residual)
template<int MODE>
__global__ __launch_bounds__(256)
void gemm_bt(const unsigned short* __restrict__ A,
             const unsigned short* __restrict__ B,
             float* __restrict__ C,
             int M, int N, int K, int ksteps_per_z,
             const float* __restrict__ bias,
             const float* __restrict__ add) {
  __shared__ unsigned short As[128 * 32];
  __shared__ unsigned short Bs[128 * 32];
  int tid = threadIdx.x;
  int w = tid >> 6, lane = tid & 63;
  int m0 = blockIdx.y * 128, n0 = blockIdx.x * 128;
  int kz0 = blockIdx.z * ksteps_per_z * 32;
  if (MODE == 0) C += (size_t)blockIdx.z * M * N;

  f32x4 zero = {0.f, 0.f, 0.f, 0.f};
  f32x4 acc[4][4];
#pragma unroll
  for (int i = 0; i < 4; ++i)
#pragma unroll
    for (int j = 0; j < 4; ++j) acc[i][j] = zero;

  int wm = w >> 1, wn = w & 1;
  int lr = lane & 15, kg = lane >> 4;

  int fe0 = (w)*512 + lane * 8;
  int fe1 = (4 + w) * 512 + lane * 8;
  int r0 = fe0 >> 5, c0 = fe0 & 31;
  int r1 = fe1 >> 5, c1 = fe1 & 31;
  const unsigned short* Ag0 = A + (size_t)(m0 + r0) * K + c0;
  const unsigned short* Ag1 = A + (size_t)(m0 + r1) * K + c1;
  const unsigned short* Bg0 = B + (size_t)(n0 + r0) * K + c0;
  const unsigned short* Bg1 = B + (size_t)(n0 + r1) * K + c1;
  unsigned short* Al0 = As + (w) * 512;
  unsigned short* Al1 = As + (4 + w) * 512;
  unsigned short* Bl0 = Bs + (w) * 512;
  unsigned short* Bl1 = Bs + (4 + w) * 512;

  for (int ks = 0; ks < ksteps_per_z; ++ks) {
    int kk = kz0 + ks * 32;
    __syncthreads();
    load_lds16(Ag0 + kk, Al0);
    load_lds16(Ag1 + kk, Al1);
    load_lds16(Bg0 + kk, Bl0);
    load_lds16(Bg1 + kk, Bl1);
    asm volatile("s_waitcnt vmcnt(0)" ::: "memory");
    __syncthreads();
    short8 a[4], b[4];
#pragma unroll
    for (int i = 0; i < 4; ++i)
      a[i] = *(const short8*)&As[(wm * 64 + i * 16 + lr) * 32 + kg * 8];
#pragma unroll
    for (int j = 0; j < 4; ++j)
      b[j] = *(const short8*)&Bs[(wn * 64 + j * 16 + lr) * 32 + kg * 8];
#pragma unroll
    for (int i = 0; i < 4; ++i)
#pragma unroll
      for (int j = 0; j < 4; ++j)
        acc[i][j] = __builtin_amdgcn_mfma_f32_16x16x32_bf16(a[i], b[j], acc[i][j], 0, 0, 0);
  }

#pragma unroll
  for (int i = 0; i < 4; ++i) {
#pragma unroll
    for (int j = 0; j < 4; ++j) {
      int rbase = m0 + wm * 64 + i * 16 + kg * 4;
      int col = n0 + wn * 64 + j * 16 + lr;
#pragma unroll
      for (int r = 0; r < 4; ++r) {
        float v = acc[i][j][r];
        size_t idx = (size_t)(rbase + r) * N + col;
        if (MODE == 0) {
          C[idx] = v;
        } else if (MODE == 1) {
          float t = v + bias[col];
          ((unsigned short*)C)[idx] = f2bf((t > 20.f) ? t : log1pf(__expf(t)));
        } else {
          C[idx] = v + add[idx];
        }
      }
    }
  }
}

// ---------------- depthwise causal conv (K=4) + SiLU -> bf16 ----------------
__global__ void conv_silu_kernel(const unsigned short* __restrict__ xin,
                                 const float* __restrict__ cw,
                                 const float* __restrict__ cb,
                                 unsigned short* __restrict__ xbf) {
  size_t idx = (size_t)blockIdx.x * blockDim.x + threadIdx.x;
  if (idx >= (size_t)NB * NL * NE) return;
  int e = (int)(idx & (NE - 1));
  int r = (int)(idx >> 12);            // b*NL + l
  int l = r & (NL - 1);
  float acc = cb[e];
#pragma unroll
  for (int k = 0; k < NKC; ++k) {
    int ls = l - 3 + k;
    if (ls >= 0) acc += bf2f(xin[(size_t)(r - 3 + k) * NE + e]) * cw[e * 4 + k];
  }
  float s = acc / (1.f + __expf(-acc));
  xbf[idx] = f2bf(s);
}

// ---------------- reduce split-K partials of the concat GEMM ----------------
__global__ void reduce_tcat_kernel(const float* __restrict__ part,
                                   unsigned short* __restrict__ tbf,
                                   float* __restrict__ bc) {
  int idx = blockIdx.x * blockDim.x + threadIdx.x;
  if (idx >= NBL * 160) return;
  int m = idx / 160, c = idx - m * 160;
  float s = 0.f;
#pragma unroll
  for (int z = 0; z < 8; ++z) s += part[(size_t)z * NBL * 256 + (size_t)m * 256 + c];
  if (c < 128) tbf[m * 128 + c] = f2bf(s);
  else if (c < 144) bc[m * 32 + (c - 128)] = s;
  else bc[m * 32 + 16 + (c - 144)] = s;
}

// ======== selective scan, 4-way L-split ========
// K1: per-segment local scan (h starts 0). seg0 rows: final gated output.
// seg>0 rows: ungated partial y (bf16). Writes fin[seg][b][e][n], dtot[seg][b][e].
__global__ __launch_bounds__(256)
void scan1_kernel(const unsigned short* __restrict__ delta_bf,
                  const unsigned short* __restrict__ x_bf,
                  const float* __restrict__ bc,
                  const float* __restrict__ gf,
                  const float* __restrict__ A_log,
                  const float* __restrict__ W_D,
                  unsigned short* __restrict__ yg,
                  float* __restrict__ fin,
                  float* __restrict__ dtot) {
  __shared__ unsigned short dxl[2][SCAN_T][2][16];  // [buf][t][{d,x}][e]
  __shared__ float gl[2][SCAN_T][16];
  __shared__ float BCl[2][SCAN_T][32];
  __shared__ float yl2[SCAN_T][16][2];              // two 8-group partials
  __shared__ float wdl[16];
  int tid = threadIdx.x;
  int n = tid & 15, el = tid >> 4;
  int w = tid >> 6, lane = tid & 63;
  int e0 = blockIdx.x * 16;
  int b = blockIdx.y >> 2, seg = blockIdx.y & 3;
  int e = e0 + el;
  float A2 = -__expf(A_log[e * 16 + n]) * 1.44269504f;
  if (tid < 16) wdl[tid] = W_D[e0 + tid];
  float h = 0.f, cum = 0.f;

  const unsigned short* gdl = delta_bf + (size_t)b * NL * NE + e0;
  const unsigned short* gx  = x_bf + (size_t)b * NL * NE + e0;
  const float* gg  = gf + (size_t)b * NL * 4096 + e0;
  const float* gBC = bc + (size_t)b * NL * 32;

  const unsigned short* dxsrc = ((lane >> 1) & 1) ? gx : gdl;
  int dxrow = w * 16 + (lane >> 2);
  int dxcol = (lane & 1) * 8;
  int grow = w * 16 + (lane >> 2);
  int gcol = (lane & 3) * 4;
  int bcrow = lane >> 3;
  int bccol = (lane & 7) * 4;

  auto stage = [&](int buf, int c) {
    int l0 = seg * SEG_T + c * SCAN_T;
    load_lds16(dxsrc + (size_t)(l0 + dxrow) * NE + dxcol, &dxl[buf][w * 16][0][0]);
    if (seg == 0)
      load_lds16(gg + (size_t)(l0 + grow) * 4096 + gcol, &gl[buf][w * 16][0]);
    load_lds16(gBC + (size_t)(l0 + w * 16 + bcrow) * 32 + bccol, &BCl[buf][w * 16][0]);
    load_lds16(gBC + (size_t)(l0 + w * 16 + 8 + bcrow) * 32 + bccol, &BCl[buf][w * 16 + 8][0]);
  };

  stage(0, 0);
  const int nch = SEG_T / SCAN_T;  // 4
  for (int c = 0; c < nch; ++c) {
    int cur = c & 1;
    if (c + 1 < nch) {
      stage(cur ^ 1, c + 1);
      if (seg == 0) { asm volatile("s_waitcnt vmcnt(4)" ::: "memory"); }
      else          { asm volatile("s_waitcnt vmcnt(3)" ::: "memory"); }
    } else {
      asm volatile("s_waitcnt vmcnt(0)" ::: "memory");
    }
    __syncthreads();
    const unsigned short (*dxc)[2][16] = dxl[cur];
    const float (*BCc)[32] = BCl[cur];
#pragma unroll 8
    for (int t = 0; t < SCAN_T; ++t) {
      float dc = bf2f(dxc[t][0][el]);
      float xc = bf2f(dxc[t][1][el]);
      float Bc = BCc[t][n];
      float Cc = BCc[t][16 + n];
      cum += dc;
      float a = dc * A2, ed;
      asm("v_exp_f32 %0, %1" : "=v"(ed) : "v"(a));   // exp2(d*A*log2e)
      h = ed * h + (dc * xc) * Bc;
      float p = h * Cc;
      p += dpp_mov<0xB1>(p);    // xor1
      p += dpp_mov<0x4E>(p);    // xor2
      p += dpp_mov<0x141>(p);   // half-mirror -> lanes 0,8 hold 8-group sums
      if ((n & 7) == 0) yl2[t][el][n >> 3] = p;
    }
    __syncthreads();
    {
      int t = tid >> 2, part = tid & 3;
      int l0 = seg * SEG_T + c * SCAN_T;
      ushort4_t o;
#pragma unroll
      for (int j = 0; j < 4; ++j) {
        int ee = part * 4 + j;
        float xv = bf2f(dxc[t][1][ee]);
        float y = yl2[t][ee][0] + yl2[t][ee][1] + xv * wdl[ee];
        if (seg == 0) y *= gl[cur][t][ee];
        o[j] = f2bf(y);
      }
      *(ushort4_t*)(yg + (size_t)(b * NL + l0 + t) * NE + e0 + part * 4) = o;
    }
    __syncthreads();
  }
  fin[(size_t)((seg * 2 + b) * 4096 + e) * 16 + n] = h;
  if (n == 0) dtot[(size_t)(seg * 2 + b) * 4096 + e] = cum;
}

// K2: fixup for segments 1..3: y_true[t] = y_part[t] + C_t . (exp(A*cumd[t]) (.) h_in),
// then gate. h_in from mini-recurrence over fin/dtot.
__global__ __launch_bounds__(256)
void scan2_kernel(const unsigned short* __restrict__ delta_bf,
                  unsigned short* __restrict__ yg,
                  const float* __restrict__ bc,
                  const float* __restrict__ gf,
                  const float* __restrict__ A_log,
                  const float* __restrict__ fin,
                  const float* __restrict__ dtot) {
  __shared__ unsigned short dl[2][SCAN_T][16];
  __shared__ unsigned short ypl[2][SCAN_T][16];
  __shared__ float Cl[2][SCAN_T][16];
  __shared__ float gl2[2][SCAN_T][16];
  __shared__ float ycl[SCAN_T][16][2];
  int tid = threadIdx.x;
  int n = tid & 15, el = tid >> 4;
  int w = tid >> 6, lane = tid & 63;
  int e0 = blockIdx.x * 16;
  int b = blockIdx.y / 3, seg = 1 + blockIdx.y % 3;
  int e = e0 + el;
  float A2 = -__expf(A_log[e * 16 + n]) * 1.44269504f;
  // h_in = state entering this segment (recurrence over per-segment locals)
  float h = fin[(size_t)(b * 4096 + e) * 16 + n];           // seg 0 final
  for (int s2 = 1; s2 < seg; ++s2) {
    float dt = dtot[(size_t)(s2 * 2 + b) * 4096 + e];
    float a = A2 * dt, pw;
    asm("v_exp_f32 %0, %1" : "=v"(pw) : "v"(a));
    h = fin[(size_t)((s2 * 2 + b) * 4096 + e) * 16 + n] + pw * h;
  }

  const unsigned short* gd = delta_bf + (size_t)b * NL * NE + e0;
  unsigned short* gy = yg + (size_t)b * NL * NE + e0;
  const float* gg  = gf + (size_t)b * NL * 4096 + e0;
  const float* gBC = bc + (size_t)b * NL * 32;

  int crow = w * 16 + (lane >> 2);
  int ccol = 16 + (lane & 3) * 4;          // C half of bc row
  int grow = w * 16 + (lane >> 2);
  int gcol = (lane & 3) * 4;
  int dyrow = (w & 1) * 32 + (lane >> 1);  // 32 rows per wave
  int dycol = (lane & 1) * 8;

  auto stage = [&](int buf, int c) {
    int l0 = seg * SEG_T + c * SCAN_T;
    load_lds16(gBC + (size_t)(l0 + crow) * 32 + ccol, &Cl[buf][w * 16][0]);
    load_lds16(gg + (size_t)(l0 + grow) * 4096 + gcol, &gl2[buf][w * 16][0]);
    if (w < 2) load_lds16(gd + (size_t)(l0 + dyrow) * NE + dycol, &dl[buf][(w & 1) * 32][0]);
    else       load_lds16(gy + (size_t)(l0 + dyrow) * NE + dycol, &ypl[buf][(w & 1) * 32][0]);
  };

  stage(0, 0);
  float cum = 0.f;
  const int nch = SEG_T / SCAN_T;  // 4
  for (int c = 0; c < nch; ++c) {
    int cur = c & 1;
    if (c + 1 < nch) {
      stage(cur ^ 1, c + 1);
      asm volatile("s_waitcnt vmcnt(3)" ::: "memory");
    } else {
      asm volatile("s_waitcnt vmcnt(0)" ::: "memory");
    }
    __syncthreads();
    const unsigned short (*dc_)[16] = dl[cur];
    const float (*Cc_)[16] = Cl[cur];
#pragma unroll 8
    for (int t = 0; t < SCAN_T; ++t) {
      float dcv = bf2f(dc_[t][el]);
      cum += dcv;
      float a = A2 * cum, pw;
      asm("v_exp_f32 %0, %1" : "=v"(pw) : "v"(a));
      float p = (pw * h) * Cc_[t][n];
      p += dpp_mov<0xB1>(p);
      p += dpp_mov<0x4E>(p);
      p += dpp_mov<0x141>(p);
      if ((n & 7) == 0) ycl[t][el][n >> 3] = p;
    }
    __syncthreads();
    {
      int t = tid >> 2, part = tid & 3;
      int l0 = seg * SEG_T + c * SCAN_T;
      ushort4_t o;
#pragma unroll
      for (int j = 0; j < 4; ++j) {
        int ee = part * 4 + j;
        float y = ycl[t][ee][0] + ycl[t][ee][1] + bf2f(ypl[cur][t][ee]);
        o[j] = f2bf(y * gl2[cur][t][ee]);
      }
      *(ushort4_t*)(gy + (size_t)(l0 + t) * NE + part * 4) = o;
    }
    __syncthreads();
  }
}

// ---------------- host launcher ----------------
extern "C" void kernel_launch(void* const* d_in, const int* in_sizes, int n_in,
                              void* d_out, int out_size, void* d_ws, size_t ws_size,
                              hipStream_t stream) {
  const float* resid  = (const float*)d_in[0];
  const float* norm_w = (const float*)d_in[1];
  const float* skip_w = (const float*)d_in[2];
  const float* in_w   = (const float*)d_in[3];
  const float* conv_w = (const float*)d_in[4];
  const float* conv_b = (const float*)d_in[5];
  const float* wd1    = (const float*)d_in[6];
  const float* wd2    = (const float*)d_in[7];
  const float* wd2_b  = (const float*)d_in[8];
  const float* wB     = (const float*)d_in[9];
  const float* wC     = (const float*)d_in[10];
  const float* A_log  = (const float*)d_in[11];
  const float* W_D    = (const float*)d_in[12];
  const float* out_w  = (const float*)d_in[13];
  float* out = (float*)d_out;

  char* ws = (char*)d_ws;
  size_t off = 0;
  auto alloc = [&](size_t bytes) -> void* {
    void* p = ws + off;
    off += (bytes + 255) & ~(size_t)255;
    return p;
  };
  unsigned short* rn_bf      = (unsigned short*)alloc((size_t)NBL * ND * 2);
  unsigned short* wskipin_bf = (unsigned short*)alloc((size_t)2 * NE * ND * 2);  // [skip_w; in_w]
  unsigned short* wout_bf    = (unsigned short*)alloc((size_t)ND * NE * 2);
  unsigned short* wd2_bf     = (unsigned short*)alloc((size_t)NE * NR * 2);
  unsigned short* wcat_bf    = (unsigned short*)alloc((size_t)256 * NE * 2);
  float* g_f                 = (float*)alloc((size_t)NBL * NE * 4);   // silu(skip)
  unsigned short* xin_bf     = (unsigned short*)alloc((size_t)NBL * NE * 2);
  unsigned short* x_bf       = (unsigned short*)alloc((size_t)NBL * NE * 2);
  float* part_f              = (float*)alloc((size_t)8 * NBL * 256 * 4);
  unsigned short* t_bf       = (unsigned short*)alloc((size_t)NBL * NR * 2);
  float* bc_f                = (float*)alloc((size_t)NBL * 32 * 4);
  unsigned short* yg_bf      = (unsigned short*)alloc((size_t)NBL * NE * 2);
  float* fin_f               = (float*)alloc((size_t)4 * NB * NE * 16 * 4);
  float* dtot_f              = (float*)alloc((size_t)4 * NB * NE * 4);
  // delta (bf16) aliases wskipin_bf: wskipin consumed by fused GEMM (step 3),
  // delta written at step 8 -> stream-ordered, safe, deterministic.
  unsigned short* delta_bf = wskipin_bf;
  (void)ws_size; (void)in_sizes; (void)n_in; (void)out_size;

  // 1. RMSNorm -> rn bf16
  rmsnorm_kernel<<<dim3(NBL), dim3(256), 0, stream>>>(resid, norm_w, rn_bf);

  // 2. weight casts
  cast_bf16_kernel<<<dim3((NE * ND / 8 + 255) / 256), dim3(256), 0, stream>>>(skip_w, wskipin_bf, NE * ND / 8);
  cast_bf16_kernel<<<dim3((NE * ND / 8 + 255) / 256), dim3(256), 0, stream>>>(in_w, wskipin_bf + (size_t)NE * ND, NE * ND / 8);
  cast_bf16_kernel<<<dim3((ND * NE / 8 + 255) / 256), dim3(256), 0, stream>>>(out_w, wout_bf, ND * NE / 8);
  cast_bf16_kernel<<<dim3((NE * NR / 8 + 255) / 256), dim3(256), 0, stream>>>(wd2, wd2_bf, NE * NR / 8);
  build_wcat_kernel<<<dim3(256 * NE / 8 / 256), dim3(256), 0, stream>>>(wd1, wB, wC, wcat_bf);

  // 3. fused [g|xin] = rn @ [skip_w; in_w]^T  (256^2 pipelined kernel)
  gemm256_fused<<<dim3(8192 / 256, NBL / 256), dim3(512), 0, stream>>>(
      rn_bf, wskipin_bf, g_f, xin_bf);

  // 5. conv + silu -> x_bf
  conv_silu_kernel<<<dim3((int)(((size_t)NB * NL * NE) / 256)), dim3(256), 0, stream>>>(
      xin_bf, conv_w, conv_b, x_bf);

  // 6. tcat = x @ [wd1;wB;wC]^T  split-K=8 -> partials
  gemm_bt<0><<<dim3(256 / 128, NBL / 128, 8), dim3(256), 0, stream>>>(
      x_bf, wcat_bf, part_f, NBL, 256, NE, (NE / 32) / 8, nullptr, nullptr);
  // 7. reduce partials -> t_bf, bc (interleaved B|C)
  reduce_tcat_kernel<<<dim3((NBL * 160 + 255) / 256), dim3(256), 0, stream>>>(
      part_f, t_bf, bc_f);

  // 8. delta = softplus(t @ wd2^T + wd2_b) -> bf16  [2048,4096] k=128
  gemm_bt<1><<<dim3(NE / 128, NBL / 128, 1), dim3(256), 0, stream>>>(
      t_bf, wd2_bf, (float*)delta_bf, NBL, NE, NR, NR / 32, wd2_b, nullptr);

  // 9a. segment-local scans (4-way L-split)
  scan1_kernel<<<dim3(NE / 16, NB * 4), dim3(256), 0, stream>>>(
      delta_bf, x_bf, bc_f, g_f, A_log, W_D, yg_bf, fin_f, dtot_f);
  // 9b. fixup segments 1..3 (+ gating)
  scan2_kernel<<<dim3(NE / 16, NB * 3), dim3(256), 0, stream>>>(
      delta_bf, yg_bf, bc_f, g_f, A_log, fin_f, dtot_f);

  // 10. out = resid + yg @ out_w^T   [2048,2048] k=4096
  gemm_bt<2><<<dim3(ND / 128, NBL / 128, 1), dim3(256), 0, stream>>>(
      yg_bf, wout_bf, out, NBL, ND, NE, NE / 32, nullptr, resid);
}

// Round 8
// 448.940 us; speedup vs baseline: 1.0318x; 1.0318x over previous
//
#include <hip/hip_runtime.h>
#include <stdint.h>

// ---- problem constants ----
#define NB 2
#define NL 1024
#define ND 2048
#define NE 4096
#define NN 16
#define NR 128
#define NKC 4
#define NBL (NB*NL)          // 2048 rows
#define EPSV 1e-5f
#define SEG_T 256            // scan L-split segment length (4 segments)
#define SCAN_T 64            // LDS chunk within a segment

typedef __attribute__((ext_vector_type(4))) float f32x4;
typedef __attribute__((ext_vector_type(8))) short short8;
typedef __attribute__((ext_vector_type(8))) unsigned short ushort8;
typedef __attribute__((ext_vector_type(4))) unsigned short ushort4_t;

__device__ __forceinline__ unsigned short f2bf(float f) {
  union { float f; unsigned u; } v; v.f = f;
  unsigned r = v.u + 0x7FFFu + ((v.u >> 16) & 1u);   // RNE
  return (unsigned short)(r >> 16);
}

__device__ __forceinline__ float bf2f(unsigned short u) {
  union { unsigned u; float f; } v; v.u = (unsigned)u << 16; return v.f;
}

__device__ __forceinline__ void load_lds16(const void* g, void* l) {
  __builtin_amdgcn_global_load_lds((const __attribute__((address_space(1))) void*)g,
                                   (__attribute__((address_space(3))) void*)l,
                                   16, 0, 0);
}

template<int CTRL>
__device__ __forceinline__ float dpp_mov(float v) {
  return __int_as_float(__builtin_amdgcn_update_dpp(
      0, __float_as_int(v), CTRL, 0xF, 0xF, true));
}

// ---------------- RMSNorm: resid[row,0:2048] -> rn_bf16 ----------------
__global__ void rmsnorm_kernel(const float* __restrict__ resid,
                               const float* __restrict__ nw,
                               unsigned short* __restrict__ rn) {
  int row = blockIdx.x;
  int tid = threadIdx.x;                 // 256 threads, 8 f32 each
  const float* r = resid + (size_t)row * ND;
  f32x4 v0 = *(const f32x4*)(r + tid * 8);
  f32x4 v1 = *(const f32x4*)(r + tid * 8 + 4);
  float vals[8];
#pragma unroll
  for (int i = 0; i < 4; ++i) { vals[i] = v0[i]; vals[4 + i] = v1[i]; }
  float ss = 0.f;
#pragma unroll
  for (int i = 0; i < 8; ++i) ss += vals[i] * vals[i];
  for (int o = 32; o > 0; o >>= 1) ss += __shfl_down(ss, o);
  __shared__ float ps[4];
  if ((tid & 63) == 0) ps[tid >> 6] = ss;
  __syncthreads();
  float tot = ps[0] + ps[1] + ps[2] + ps[3];
  float scale = rsqrtf(tot / (float)ND + EPSV);
  ushort8 o8;
#pragma unroll
  for (int i = 0; i < 8; ++i) o8[i] = f2bf(vals[i] * scale * nw[tid * 8 + i]);
  *(ushort8*)(rn + (size_t)row * ND + tid * 8) = o8;
}

// ---------------- generic f32 -> bf16 cast (8 elems/thread) ----------------
__global__ void cast_bf16_kernel(const float* __restrict__ in,
                                 unsigned short* __restrict__ out, int n8) {
  int i = blockIdx.x * blockDim.x + threadIdx.x;
  if (i >= n8) return;
  f32x4 a = *(const f32x4*)(in + (size_t)i * 8);
  f32x4 b = *(const f32x4*)(in + (size_t)i * 8 + 4);
  ushort8 o;
#pragma unroll
  for (int j = 0; j < 4; ++j) { o[j] = f2bf(a[j]); o[4 + j] = f2bf(b[j]); }
  *(ushort8*)(out + (size_t)i * 8) = o;
}

// ---- build concatenated [256 x 4096] bf16 weight: rows 0-127 wd1, 128-143 wB, 144-159 wC, rest 0
__global__ void build_wcat_kernel(const float* __restrict__ wd1,
                                  const float* __restrict__ wB,
                                  const float* __restrict__ wC,
                                  unsigned short* __restrict__ out) {
  int i = blockIdx.x * blockDim.x + threadIdx.x;   // total 256*4096/8 = 131072
  if (i >= 256 * NE / 8) return;
  int col8 = i & (NE / 8 - 1);
  int row = i >> 9;
  const float* src = nullptr; int srow = 0;
  if (row < 128)      { src = wd1; srow = row; }
  else if (row < 144) { src = wB;  srow = row - 128; }
  else if (row < 160) { src = wC;  srow = row - 144; }
  ushort8 o;
  if (src) {
    f32x4 a = *(const f32x4*)(src + (size_t)srow * NE + col8 * 8);
    f32x4 b = *(const f32x4*)(src + (size_t)srow * NE + col8 * 8 + 4);
#pragma unroll
    for (int j = 0; j < 4; ++j) { o[j] = f2bf(a[j]); o[4 + j] = f2bf(b[j]); }
  } else {
#pragma unroll
    for (int j = 0; j < 8; ++j) o[j] = 0;
  }
  *(ushort8*)(out + (size_t)row * NE + col8 * 8) = o;
}

// ======== 256x256 multi-phase counted-vmcnt GEMM (fused skip+in proj) ========
__global__ __launch_bounds__(512, 2)
void gemm256_fused(const unsigned short* __restrict__ A,
                   const unsigned short* __restrict__ B,
                   float* __restrict__ Gout,
                   unsigned short* __restrict__ Xout) {
  const int K = 2048, NH = K / 32;   // 64 K-halves
  __shared__ unsigned short Asl[4][8192];   // [slot][r*32+c]  r<256, c<32
  __shared__ unsigned short Bsl[4][8192];
  int tid = threadIdx.x;
  int w = tid >> 6, lane = tid & 63;
  int wm = w >> 2, wn = w & 3;
  int lr = lane & 15, kg8 = (lane >> 4) * 8;
  int m0 = blockIdx.y * 256, n0 = blockIdx.x * 256;

  const unsigned short* ga = A + (size_t)(m0 + (tid >> 2)) * K + (tid & 3) * 8;
  const unsigned short* gb = B + (size_t)(n0 + (tid >> 2)) * K + (tid & 3) * 8;
  char* ldsA0 = (char*)&Asl[0][0] + w * 1024;
  char* ldsB0 = (char*)&Bsl[0][0] + w * 1024;

  auto stageA = [&](int h) {
    int slot = h & 3, k0 = h * 32;
    load_lds16(ga + k0, ldsA0 + slot * 16384);
    load_lds16(ga + k0 + (size_t)128 * K, ldsA0 + slot * 16384 + 8192);
  };
  auto stageB = [&](int h) {
    int slot = h & 3, k0 = h * 32;
    load_lds16(gb + k0, ldsB0 + slot * 16384);
    load_lds16(gb + k0 + (size_t)128 * K, ldsB0 + slot * 16384 + 8192);
  };

  f32x4 acc[8][4];
#pragma unroll
  for (int i = 0; i < 8; ++i)
#pragma unroll
    for (int j = 0; j < 4; ++j) acc[i][j] = (f32x4){0.f, 0.f, 0.f, 0.f};

  stageA(0); stageB(0); stageA(1); stageB(1); stageA(2); stageB(2);
  asm volatile("s_waitcnt vmcnt(8)" ::: "memory");
  __builtin_amdgcn_s_barrier();

  for (int h = 0; h < NH; ++h) {
    int slot = h & 3;
    const unsigned short* As_ = &Asl[slot][0];
    const unsigned short* Bs_ = &Bsl[slot][0];
    int arow = wm * 128 + lr;
    int brow = wn * 64 + lr;
    short8 a[8], b[4];
#pragma unroll
    for (int i = 0; i < 4; ++i)
      a[i] = *(const short8*)&As_[(arow + i * 16) * 32 + kg8];
#pragma unroll
    for (int j = 0; j < 4; ++j)
      b[j] = *(const short8*)&Bs_[(brow + j * 16) * 32 + kg8];
    if (h + 3 < NH) stageA(h + 3);
    __builtin_amdgcn_s_barrier();
    __builtin_amdgcn_s_setprio(1);
#pragma unroll
    for (int i = 0; i < 4; ++i)
#pragma unroll
      for (int j = 0; j < 4; ++j)
        acc[i][j] = __builtin_amdgcn_mfma_f32_16x16x32_bf16(a[i], b[j], acc[i][j], 0, 0, 0);
    __builtin_amdgcn_s_setprio(0);
    __builtin_amdgcn_s_barrier();
#pragma unroll
    for (int i = 0; i < 4; ++i)
      a[4 + i] = *(const short8*)&As_[(arow + (4 + i) * 16) * 32 + kg8];
    if (h + 3 < NH) stageB(h + 3);
    __builtin_amdgcn_s_barrier();
    __builtin_amdgcn_s_setprio(1);
#pragma unroll
    for (int i = 0; i < 4; ++i)
#pragma unroll
      for (int j = 0; j < 4; ++j)
        acc[4 + i][j] = __builtin_amdgcn_mfma_f32_16x16x32_bf16(a[4 + i], b[j], acc[4 + i][j], 0, 0, 0);
    __builtin_amdgcn_s_setprio(0);
    if (h < NH - 3)       { asm volatile("s_waitcnt vmcnt(8)" ::: "memory"); }
    else if (h == NH - 3) { asm volatile("s_waitcnt vmcnt(4)" ::: "memory"); }
    else if (h == NH - 2) { asm volatile("s_waitcnt vmcnt(0)" ::: "memory"); }
    __builtin_amdgcn_s_barrier();
  }

  int rbase = m0 + wm * 128 + (lane >> 4) * 4;
  int cbase = n0 + wn * 64 + (lane & 15);
  bool isg = (n0 < 4096);
#pragma unroll
  for (int mf = 0; mf < 8; ++mf) {
#pragma unroll
    for (int nf = 0; nf < 4; ++nf) {
      int col = cbase + nf * 16;
#pragma unroll
      for (int rr = 0; rr < 4; ++rr) {
        int row = rbase + mf * 16 + rr;
        float v = acc[mf][nf][rr];
        if (isg) Gout[(size_t)row * 4096 + col] = v / (1.f + __expf(-v));
        else     Xout[(size_t)row * 4096 + (col - 4096)] = f2bf(v);
      }
    }
  }
}

// ---------------- bf16 MFMA GEMM, 4-slot ring pipeline (T3+T4+T5) ----------------
// C[M,N] = A[M,K] @ B[N,K]^T. 128x128 tile, 256 threads (4 waves 2x2), BK=32.
// Ring of 4 K-slots; stage slot h+3 during h; counted vmcnt (12/8/4/0 tail);
// raw s_barrier only (no full drain mid-loop).
// MODE 0: plain f32 store (split-K via blockIdx.z); MODE 1: softplus->bf16;
// MODE 2: acc + add (residual)
template<int MODE>
__global__ __launch_bounds__(256)
void gemm_bt(const unsigned short* __restrict__ A,
             const unsigned short* __restrict__ B,
             float* __restrict__ C,
             int M, int N, int K, int ksteps_per_z,
             const float* __restrict__ bias,
             const float* __restrict__ add) {
  __shared__ unsigned short As[4][128 * 32];
  __shared__ unsigned short Bs[4][128 * 32];
  int tid = threadIdx.x;
  int w = tid >> 6, lane = tid & 63;
  int m0 = blockIdx.y * 128, n0 = blockIdx.x * 128;
  int kz0 = blockIdx.z * ksteps_per_z * 32;
  if (MODE == 0) C += (size_t)blockIdx.z * M * N;
  const int NH = ksteps_per_z;

  f32x4 acc[4][4];
#pragma unroll
  for (int i = 0; i < 4; ++i)
#pragma unroll
    for (int j = 0; j < 4; ++j) acc[i][j] = (f32x4){0.f, 0.f, 0.f, 0.f};

  int wm = w >> 1, wn = w & 1;
  int lr = lane & 15, kg = lane >> 4;

  // staging geometry: issue i (0,1): flat elem = (i*4+w)*512 + lane*8
  int fe0 = (w) * 512 + lane * 8;
  int fe1 = (4 + w) * 512 + lane * 8;
  int r0 = fe0 >> 5, c0 = fe0 & 31;
  int r1 = fe1 >> 5, c1 = fe1 & 31;
  const unsigned short* Ag0 = A + (size_t)(m0 + r0) * K + c0 + kz0;
  const unsigned short* Ag1 = A + (size_t)(m0 + r1) * K + c1 + kz0;
  const unsigned short* Bg0 = B + (size_t)(n0 + r0) * K + c0 + kz0;
  const unsigned short* Bg1 = B + (size_t)(n0 + r1) * K + c1 + kz0;

  auto stage = [&](int h) {
    int slot = h & 3, kk = h * 32;
    load_lds16(Ag0 + kk, &As[slot][(w) * 512]);
    load_lds16(Ag1 + kk, &As[slot][(4 + w) * 512]);
    load_lds16(Bg0 + kk, &Bs[slot][(w) * 512]);
    load_lds16(Bg1 + kk, &Bs[slot][(4 + w) * 512]);
  };

  // prologue: 3 slots in flight
  stage(0);
  if (NH > 1) stage(1);
  if (NH > 2) stage(2);

  for (int h = 0; h < NH; ++h) {
    int slot = h & 3;
    __builtin_amdgcn_s_barrier();        // all waves done reading slot (h-1)&3
    if (h + 3 < NH) stage(h + 3);        // safe to overwrite it now
    int rem = NH - 1 - h; if (rem > 3) rem = 3;
    if (rem == 3)      { asm volatile("s_waitcnt vmcnt(12)" ::: "memory"); }
    else if (rem == 2) { asm volatile("s_waitcnt vmcnt(8)"  ::: "memory"); }
    else if (rem == 1) { asm volatile("s_waitcnt vmcnt(4)"  ::: "memory"); }
    else               { asm volatile("s_waitcnt vmcnt(0)"  ::: "memory"); }
    __builtin_amdgcn_s_barrier();        // slot h fully landed for all waves
    short8 a[4], b[4];
#pragma unroll
    for (int i = 0; i < 4; ++i)
      a[i] = *(const short8*)&As[slot][(wm * 64 + i * 16 + lr) * 32 + kg * 8];
#pragma unroll
    for (int j = 0; j < 4; ++j)
      b[j] = *(const short8*)&Bs[slot][(wn * 64 + j * 16 + lr) * 32 + kg * 8];
    __builtin_amdgcn_s_setprio(1);
#pragma unroll
    for (int i = 0; i < 4; ++i)
#pragma unroll
      for (int j = 0; j < 4; ++j)
        acc[i][j] = __builtin_amdgcn_mfma_f32_16x16x32_bf16(a[i], b[j], acc[i][j], 0, 0, 0);
    __builtin_amdgcn_s_setprio(0);
  }

  // epilogue: C/D layout col=lane&15, row=(lane>>4)*4+reg  (verified m89/m91)
#pragma unroll
  for (int i = 0; i < 4; ++i) {
#pragma unroll
    for (int j = 0; j < 4; ++j) {
      int rbase = m0 + wm * 64 + i * 16 + kg * 4;
      int col = n0 + wn * 64 + j * 16 + lr;
#pragma unroll
      for (int r = 0; r < 4; ++r) {
        float v = acc[i][j][r];
        size_t idx = (size_t)(rbase + r) * N + col;
        if (MODE == 0) {
          C[idx] = v;
        } else if (MODE == 1) {
          float t = v + bias[col];
          ((unsigned short*)C)[idx] = f2bf((t > 20.f) ? t : log1pf(__expf(t)));
        } else {
          C[idx] = v + add[idx];
        }
      }
    }
  }
}

// ---------------- depthwise causal conv (K=4) + SiLU -> bf16 ----------------
__global__ void conv_silu_kernel(const unsigned short* __restrict__ xin,
                                 const float* __restrict__ cw,
                                 const float* __restrict__ cb,
                                 unsigned short* __restrict__ xbf) {
  size_t idx = (size_t)blockIdx.x * blockDim.x + threadIdx.x;
  if (idx >= (size_t)NB * NL * NE) return;
  int e = (int)(idx & (NE - 1));
  int r = (int)(idx >> 12);            // b*NL + l
  int l = r & (NL - 1);
  float acc = cb[e];
#pragma unroll
  for (int k = 0; k < NKC; ++k) {
    int ls = l - 3 + k;
    if (ls >= 0) acc += bf2f(xin[(size_t)(r - 3 + k) * NE + e]) * cw[e * 4 + k];
  }
  float s = acc / (1.f + __expf(-acc));
  xbf[idx] = f2bf(s);
}

// ---------------- reduce split-K partials of the concat GEMM ----------------
__global__ void reduce_tcat_kernel(const float* __restrict__ part,
                                   unsigned short* __restrict__ tbf,
                                   float* __restrict__ bc) {
  int idx = blockIdx.x * blockDim.x + threadIdx.x;
  if (idx >= NBL * 160) return;
  int m = idx / 160, c = idx - m * 160;
  float s = 0.f;
#pragma unroll
  for (int z = 0; z < 8; ++z) s += part[(size_t)z * NBL * 256 + (size_t)m * 256 + c];
  if (c < 128) tbf[m * 128 + c] = f2bf(s);
  else if (c < 144) bc[m * 32 + (c - 128)] = s;
  else bc[m * 32 + 16 + (c - 144)] = s;
}

// ======== selective scan, 4-way L-split ========
// K1: per-segment local scan (h starts 0). seg0 rows: final gated output.
// seg>0 rows: ungated partial y (bf16). Writes fin[seg][b][e][n], dtot[seg][b][e].
__global__ __launch_bounds__(256)
void scan1_kernel(const unsigned short* __restrict__ delta_bf,
                  const unsigned short* __restrict__ x_bf,
                  const float* __restrict__ bc,
                  const float* __restrict__ gf,
                  const float* __restrict__ A_log,
                  const float* __restrict__ W_D,
                  unsigned short* __restrict__ yg,
                  float* __restrict__ fin,
                  float* __restrict__ dtot) {
  __shared__ unsigned short dxl[2][SCAN_T][2][16];  // [buf][t][{d,x}][e]
  __shared__ float gl[2][SCAN_T][16];
  __shared__ float BCl[2][SCAN_T][32];
  __shared__ float yl2[SCAN_T][16][2];              // two 8-group partials
  __shared__ float wdl[16];
  int tid = threadIdx.x;
  int n = tid & 15, el = tid >> 4;
  int w = tid >> 6, lane = tid & 63;
  int e0 = blockIdx.x * 16;
  int b = blockIdx.y >> 2, seg = blockIdx.y & 3;
  int e = e0 + el;
  float A2 = -__expf(A_log[e * 16 + n]) * 1.44269504f;
  if (tid < 16) wdl[tid] = W_D[e0 + tid];
  float h = 0.f, cum = 0.f;

  const unsigned short* gdl = delta_bf + (size_t)b * NL * NE + e0;
  const unsigned short* gx  = x_bf + (size_t)b * NL * NE + e0;
  const float* gg  = gf + (size_t)b * NL * 4096 + e0;
  const float* gBC = bc + (size_t)b * NL * 32;

  const unsigned short* dxsrc = ((lane >> 1) & 1) ? gx : gdl;
  int dxrow = w * 16 + (lane >> 2);
  int dxcol = (lane & 1) * 8;
  int grow = w * 16 + (lane >> 2);
  int gcol = (lane & 3) * 4;
  int bcrow = lane >> 3;
  int bccol = (lane & 7) * 4;

  auto stage = [&](int buf, int c) {
    int l0 = seg * SEG_T + c * SCAN_T;
    load_lds16(dxsrc + (size_t)(l0 + dxrow) * NE + dxcol, &dxl[buf][w * 16][0][0]);
    if (seg == 0)
      load_lds16(gg + (size_t)(l0 + grow) * 4096 + gcol, &gl[buf][w * 16][0]);
    load_lds16(gBC + (size_t)(l0 + w * 16 + bcrow) * 32 + bccol, &BCl[buf][w * 16][0]);
    load_lds16(gBC + (size_t)(l0 + w * 16 + 8 + bcrow) * 32 + bccol, &BCl[buf][w * 16 + 8][0]);
  };

  stage(0, 0);
  const int nch = SEG_T / SCAN_T;  // 4
  for (int c = 0; c < nch; ++c) {
    int cur = c & 1;
    if (c + 1 < nch) {
      stage(cur ^ 1, c + 1);
      if (seg == 0) { asm volatile("s_waitcnt vmcnt(4)" ::: "memory"); }
      else          { asm volatile("s_waitcnt vmcnt(3)" ::: "memory"); }
    } else {
      asm volatile("s_waitcnt vmcnt(0)" ::: "memory");
    }
    __syncthreads();
    const unsigned short (*dxc)[2][16] = dxl[cur];
    const float (*BCc)[32] = BCl[cur];
#pragma unroll 8
    for (int t = 0; t < SCAN_T; ++t) {
      float dc = bf2f(dxc[t][0][el]);
      float xc = bf2f(dxc[t][1][el]);
      float Bc = BCc[t][n];
      float Cc = BCc[t][16 + n];
      cum += dc;
      float a = dc * A2, ed;
      asm("v_exp_f32 %0, %1" : "=v"(ed) : "v"(a));   // exp2(d*A*log2e)
      h = ed * h + (dc * xc) * Bc;
      float p = h * Cc;
      p += dpp_mov<0xB1>(p);    // xor1
      p += dpp_mov<0x4E>(p);    // xor2
      p += dpp_mov<0x141>(p);   // half-mirror -> lanes 0,8 hold 8-group sums
      if ((n & 7) == 0) yl2[t][el][n >> 3] = p;
    }
    __syncthreads();
    {
      int t = tid >> 2, part = tid & 3;
      int l0 = seg * SEG_T + c * SCAN_T;
      ushort4_t o;
#pragma unroll
      for (int j = 0; j < 4; ++j) {
        int ee = part * 4 + j;
        float xv = bf2f(dxc[t][1][ee]);
        float y = yl2[t][ee][0] + yl2[t][ee][1] + xv * wdl[ee];
        if (seg == 0) y *= gl[cur][t][ee];
        o[j] = f2bf(y);
      }
      *(ushort4_t*)(yg + (size_t)(b * NL + l0 + t) * NE + e0 + part * 4) = o;
    }
    __syncthreads();
  }
  fin[(size_t)((seg * 2 + b) * 4096 + e) * 16 + n] = h;
  if (n == 0) dtot[(size_t)(seg * 2 + b) * 4096 + e] = cum;
}

// K2: fixup for segments 1..3: y_true[t] = y_part[t] + C_t . (exp(A*cumd[t]) (.) h_in),
// then gate. h_in from mini-recurrence over fin/dtot.
__global__ __launch_bounds__(256)
void scan2_kernel(const unsigned short* __restrict__ delta_bf,
                  unsigned short* __restrict__ yg,
                  const float* __restrict__ bc,
                  const float* __restrict__ gf,
                  const float* __restrict__ A_log,
                  const float* __restrict__ fin,
                  const float* __restrict__ dtot) {
  __shared__ unsigned short dl[2][SCAN_T][16];
  __shared__ unsigned short ypl[2][SCAN_T][16];
  __shared__ float Cl[2][SCAN_T][16];
  __shared__ float gl2[2][SCAN_T][16];
  __shared__ float ycl[SCAN_T][16][2];
  int tid = threadIdx.x;
  int n = tid & 15, el = tid >> 4;
  int w = tid >> 6, lane = tid & 63;
  int e0 = blockIdx.x * 16;
  int b = blockIdx.y / 3, seg = 1 + blockIdx.y % 3;
  int e = e0 + el;
  float A2 = -__expf(A_log[e * 16 + n]) * 1.44269504f;
  // h_in = state entering this segment (recurrence over per-segment locals)
  float h = fin[(size_t)(b * 4096 + e) * 16 + n];           // seg 0 final
  for (int s2 = 1; s2 < seg; ++s2) {
    float dt = dtot[(size_t)(s2 * 2 + b) * 4096 + e];
    float a = A2 * dt, pw;
    asm("v_exp_f32 %0, %1" : "=v"(pw) : "v"(a));
    h = fin[(size_t)((s2 * 2 + b) * 4096 + e) * 16 + n] + pw * h;
  }

  const unsigned short* gd = delta_bf + (size_t)b * NL * NE + e0;
  unsigned short* gy = yg + (size_t)b * NL * NE + e0;
  const float* gg  = gf + (size_t)b * NL * 4096 + e0;
  const float* gBC = bc + (size_t)b * NL * 32;

  int crow = w * 16 + (lane >> 2);
  int ccol = 16 + (lane & 3) * 4;          // C half of bc row
  int grow = w * 16 + (lane >> 2);
  int gcol = (lane & 3) * 4;
  int dyrow = (w & 1) * 32 + (lane >> 1);  // 32 rows per wave
  int dycol = (lane & 1) * 8;

  auto stage = [&](int buf, int c) {
    int l0 = seg * SEG_T + c * SCAN_T;
    load_lds16(gBC + (size_t)(l0 + crow) * 32 + ccol, &Cl[buf][w * 16][0]);
    load_lds16(gg + (size_t)(l0 + grow) * 4096 + gcol, &gl2[buf][w * 16][0]);
    if (w < 2) load_lds16(gd + (size_t)(l0 + dyrow) * NE + dycol, &dl[buf][(w & 1) * 32][0]);
    else       load_lds16(gy + (size_t)(l0 + dyrow) * NE + dycol, &ypl[buf][(w & 1) * 32][0]);
  };

  stage(0, 0);
  float cum = 0.f;
  const int nch = SEG_T / SCAN_T;  // 4
  for (int c = 0; c < nch; ++c) {
    int cur = c & 1;
    if (c + 1 < nch) {
      stage(cur ^ 1, c + 1);
      asm volatile("s_waitcnt vmcnt(3)" ::: "memory");
    } else {
      asm volatile("s_waitcnt vmcnt(0)" ::: "memory");
    }
    __syncthreads();
    const unsigned short (*dc_)[16] = dl[cur];
    const float (*Cc_)[16] = Cl[cur];
#pragma unroll 8
    for (int t = 0; t < SCAN_T; ++t) {
      float dcv = bf2f(dc_[t][el]);
      cum += dcv;
      float a = A2 * cum, pw;
      asm("v_exp_f32 %0, %1" : "=v"(pw) : "v"(a));
      float p = (pw * h) * Cc_[t][n];
      p += dpp_mov<0xB1>(p);
      p += dpp_mov<0x4E>(p);
      p += dpp_mov<0x141>(p);
      if ((n & 7) == 0) ycl[t][el][n >> 3] = p;
    }
    __syncthreads();
    {
      int t = tid >> 2, part = tid & 3;
      int l0 = seg * SEG_T + c * SCAN_T;
      ushort4_t o;
#pragma unroll
      for (int j = 0; j < 4; ++j) {
        int ee = part * 4 + j;
        float y = ycl[t][ee][0] + ycl[t][ee][1] + bf2f(ypl[cur][t][ee]);
        o[j] = f2bf(y * gl2[cur][t][ee]);
      }
      *(ushort4_t*)(gy + (size_t)(l0 + t) * NE + part * 4) = o;
    }
    __syncthreads();
  }
}

// ---------------- host launcher ----------------
extern "C" void kernel_launch(void* const* d_in, const int* in_sizes, int n_in,
                              void* d_out, int out_size, void* d_ws, size_t ws_size,
                              hipStream_t stream) {
  const float* resid  = (const float*)d_in[0];
  const float* norm_w = (const float*)d_in[1];
  const float* skip_w = (const float*)d_in[2];
  const float* in_w   = (const float*)d_in[3];
  const float* conv_w = (const float*)d_in[4];
  const float* conv_b = (const float*)d_in[5];
  const float* wd1    = (const float*)d_in[6];
  const float* wd2    = (const float*)d_in[7];
  const float* wd2_b  = (const float*)d_in[8];
  const float* wB     = (const float*)d_in[9];
  const float* wC     = (const float*)d_in[10];
  const float* A_log  = (const float*)d_in[11];
  const float* W_D    = (const float*)d_in[12];
  const float* out_w  = (const float*)d_in[13];
  float* out = (float*)d_out;

  char* ws = (char*)d_ws;
  size_t off = 0;
  auto alloc = [&](size_t bytes) -> void* {
    void* p = ws + off;
    off += (bytes + 255) & ~(size_t)255;
    return p;
  };
  unsigned short* rn_bf      = (unsigned short*)alloc((size_t)NBL * ND * 2);
  unsigned short* wskipin_bf = (unsigned short*)alloc((size_t)2 * NE * ND * 2);  // [skip_w; in_w]
  unsigned short* wout_bf    = (unsigned short*)alloc((size_t)ND * NE * 2);
  unsigned short* wd2_bf     = (unsigned short*)alloc((size_t)NE * NR * 2);
  unsigned short* wcat_bf    = (unsigned short*)alloc((size_t)256 * NE * 2);
  float* g_f                 = (float*)alloc((size_t)NBL * NE * 4);   // silu(skip)
  unsigned short* xin_bf     = (unsigned short*)alloc((size_t)NBL * NE * 2);
  unsigned short* x_bf       = (unsigned short*)alloc((size_t)NBL * NE * 2);
  float* part_f              = (float*)alloc((size_t)8 * NBL * 256 * 4);
  unsigned short* t_bf       = (unsigned short*)alloc((size_t)NBL * NR * 2);
  float* bc_f                = (float*)alloc((size_t)NBL * 32 * 4);
  unsigned short* yg_bf      = (unsigned short*)alloc((size_t)NBL * NE * 2);
  float* fin_f               = (float*)alloc((size_t)4 * NB * NE * 16 * 4);
  float* dtot_f              = (float*)alloc((size_t)4 * NB * NE * 4);
  // delta (bf16) aliases wskipin_bf: wskipin consumed by fused GEMM (step 3),
  // delta written at step 8 -> stream-ordered, safe, deterministic.
  unsigned short* delta_bf = wskipin_bf;
  (void)ws_size; (void)in_sizes; (void)n_in; (void)out_size;

  // 1. RMSNorm -> rn bf16
  rmsnorm_kernel<<<dim3(NBL), dim3(256), 0, stream>>>(resid, norm_w, rn_bf);

  // 2. weight casts
  cast_bf16_kernel<<<dim3((NE * ND / 8 + 255) / 256), dim3(256), 0, stream>>>(skip_w, wskipin_bf, NE * ND / 8);
  cast_bf16_kernel<<<dim3((NE * ND / 8 + 255) / 256), dim3(256), 0, stream>>>(in_w, wskipin_bf + (size_t)NE * ND, NE * ND / 8);
  cast_bf16_kernel<<<dim3((ND * NE / 8 + 255) / 256), dim3(256), 0, stream>>>(out_w, wout_bf, ND * NE / 8);
  cast_bf16_kernel<<<dim3((NE * NR / 8 + 255) / 256), dim3(256), 0, stream>>>(wd2, wd2_bf, NE * NR / 8);
  build_wcat_kernel<<<dim3(256 * NE / 8 / 256), dim3(256), 0, stream>>>(wd1, wB, wC, wcat_bf);

  // 3. fused [g|xin] = rn @ [skip_w; in_w]^T  (256^2 pipelined kernel)
  gemm256_fused<<<dim3(8192 / 256, NBL / 256), dim3(512), 0, stream>>>(
      rn_bf, wskipin_bf, g_f, xin_bf);

  // 5. conv + silu -> x_bf
  conv_silu_kernel<<<dim3((int)(((size_t)NB * NL * NE) / 256)), dim3(256), 0, stream>>>(
      xin_bf, conv_w, conv_b, x_bf);

  // 6. tcat = x @ [wd1;wB;wC]^T  split-K=8 -> partials
  gemm_bt<0><<<dim3(256 / 128, NBL / 128, 8), dim3(256), 0, stream>>>(
      x_bf, wcat_bf, part_f, NBL, 256, NE, (NE / 32) / 8, nullptr, nullptr);
  // 7. reduce partials -> t_bf, bc (interleaved B|C)
  reduce_tcat_kernel<<<dim3((NBL * 160 + 255) / 256), dim3(256), 0, stream>>>(
      part_f, t_bf, bc_f);

  // 8. delta = softplus(t @ wd2^T + wd2_b) -> bf16  [2048,4096] k=128
  gemm_bt<1><<<dim3(NE / 128, NBL / 128, 1), dim3(256), 0, stream>>>(
      t_bf, wd2_bf, (float*)delta_bf, NBL, NE, NR, NR / 32, wd2_b, nullptr);

  // 9a. segment-local scans (4-way L-split)
  scan1_kernel<<<dim3(NE / 16, NB * 4), dim3(256), 0, stream>>>(
      delta_bf, x_bf, bc_f, g_f, A_log, W_D, yg_bf, fin_f, dtot_f);
  // 9b. fixup segments 1..3 (+ gating)
  scan2_kernel<<<dim3(NE / 16, NB * 3), dim3(256), 0, stream>>>(
      delta_bf, yg_bf, bc_f, g_f, A_log, fin_f, dtot_f);

  // 10. out = resid + yg @ out_w^T   [2048,2048] k=4096
  gemm_bt<2><<<dim3(ND / 128, NBL / 128, 1), dim3(256), 0, stream>>>(
      yg_bf, wout_bf, out, NBL, ND, NE, NE / 32, nullptr, resid);
}

// Round 9
// 419.297 us; speedup vs baseline: 1.1048x; 1.0707x over previous
//
#include <hip/hip_runtime.h>
#include <stdint.h>

// ---- problem constants ----
#define NB 2
#define NL 1024
#define ND 2048
#define NE 4096
#define NN 16
#define NR 128
#define NKC 4
#define NBL (NB*NL)          // 2048 rows
#define EPSV 1e-5f
#define SEG_T 256            // scan L-split segment length (4 segments)
#define SCAN_T 32            // LDS chunk within a segment (small -> high occupancy)

typedef __attribute__((ext_vector_type(4))) float f32x4;
typedef __attribute__((ext_vector_type(8))) short short8;
typedef __attribute__((ext_vector_type(8))) unsigned short ushort8;
typedef __attribute__((ext_vector_type(4))) unsigned short ushort4_t;
typedef __attribute__((ext_vector_type(2))) unsigned short ushort2_t;

__device__ __forceinline__ unsigned short f2bf(float f) {
  union { float f; unsigned u; } v; v.f = f;
  unsigned r = v.u + 0x7FFFu + ((v.u >> 16) & 1u);   // RNE
  return (unsigned short)(r >> 16);
}

__device__ __forceinline__ float bf2f(unsigned short u) {
  union { unsigned u; float f; } v; v.u = (unsigned)u << 16; return v.f;
}

__device__ __forceinline__ void load_lds16(const void* g, void* l) {
  __builtin_amdgcn_global_load_lds((const __attribute__((address_space(1))) void*)g,
                                   (__attribute__((address_space(3))) void*)l,
                                   16, 0, 0);
}

template<int CTRL>
__device__ __forceinline__ float dpp_mov(float v) {
  return __int_as_float(__builtin_amdgcn_update_dpp(
      0, __float_as_int(v), CTRL, 0xF, 0xF, true));
}

// ---------------- RMSNorm: resid[row,0:2048] -> rn_bf16 ----------------
__global__ void rmsnorm_kernel(const float* __restrict__ resid,
                               const float* __restrict__ nw,
                               unsigned short* __restrict__ rn) {
  int row = blockIdx.x;
  int tid = threadIdx.x;                 // 256 threads, 8 f32 each
  const float* r = resid + (size_t)row * ND;
  f32x4 v0 = *(const f32x4*)(r + tid * 8);
  f32x4 v1 = *(const f32x4*)(r + tid * 8 + 4);
  float vals[8];
#pragma unroll
  for (int i = 0; i < 4; ++i) { vals[i] = v0[i]; vals[4 + i] = v1[i]; }
  float ss = 0.f;
#pragma unroll
  for (int i = 0; i < 8; ++i) ss += vals[i] * vals[i];
  for (int o = 32; o > 0; o >>= 1) ss += __shfl_down(ss, o);
  __shared__ float ps[4];
  if ((tid & 63) == 0) ps[tid >> 6] = ss;
  __syncthreads();
  float tot = ps[0] + ps[1] + ps[2] + ps[3];
  float scale = rsqrtf(tot / (float)ND + EPSV);
  ushort8 o8;
#pragma unroll
  for (int i = 0; i < 8; ++i) o8[i] = f2bf(vals[i] * scale * nw[tid * 8 + i]);
  *(ushort8*)(rn + (size_t)row * ND + tid * 8) = o8;
}

// ---------------- generic f32 -> bf16 cast (8 elems/thread) ----------------
__global__ void cast_bf16_kernel(const float* __restrict__ in,
                                 unsigned short* __restrict__ out, int n8) {
  int i = blockIdx.x * blockDim.x + threadIdx.x;
  if (i >= n8) return;
  f32x4 a = *(const f32x4*)(in + (size_t)i * 8);
  f32x4 b = *(const f32x4*)(in + (size_t)i * 8 + 4);
  ushort8 o;
#pragma unroll
  for (int j = 0; j < 4; ++j) { o[j] = f2bf(a[j]); o[4 + j] = f2bf(b[j]); }
  *(ushort8*)(out + (size_t)i * 8) = o;
}

// ---- build concatenated [256 x 4096] bf16 weight: rows 0-127 wd1, 128-143 wB, 144-159 wC, rest 0
__global__ void build_wcat_kernel(const float* __restrict__ wd1,
                                  const float* __restrict__ wB,
                                  const float* __restrict__ wC,
                                  unsigned short* __restrict__ out) {
  int i = blockIdx.x * blockDim.x + threadIdx.x;   // total 256*4096/8 = 131072
  if (i >= 256 * NE / 8) return;
  int col8 = i & (NE / 8 - 1);
  int row = i >> 9;
  const float* src = nullptr; int srow = 0;
  if (row < 128)      { src = wd1; srow = row; }
  else if (row < 144) { src = wB;  srow = row - 128; }
  else if (row < 160) { src = wC;  srow = row - 144; }
  ushort8 o;
  if (src) {
    f32x4 a = *(const f32x4*)(src + (size_t)srow * NE + col8 * 8);
    f32x4 b = *(const f32x4*)(src + (size_t)srow * NE + col8 * 8 + 4);
#pragma unroll
    for (int j = 0; j < 4; ++j) { o[j] = f2bf(a[j]); o[4 + j] = f2bf(b[j]); }
  } else {
#pragma unroll
    for (int j = 0; j < 8; ++j) o[j] = 0;
  }
  *(ushort8*)(out + (size_t)row * NE + col8 * 8) = o;
}

// ======== 256x256 multi-phase counted-vmcnt GEMM (fused skip+in proj) ========
__global__ __launch_bounds__(512, 2)
void gemm256_fused(const unsigned short* __restrict__ A,
                   const unsigned short* __restrict__ B,
                   float* __restrict__ Gout,
                   unsigned short* __restrict__ Xout) {
  const int K = 2048, NH = K / 32;   // 64 K-halves
  __shared__ unsigned short Asl[4][8192];   // [slot][r*32+c]  r<256, c<32
  __shared__ unsigned short Bsl[4][8192];
  int tid = threadIdx.x;
  int w = tid >> 6, lane = tid & 63;
  int wm = w >> 2, wn = w & 3;
  int lr = lane & 15, kg8 = (lane >> 4) * 8;
  int m0 = blockIdx.y * 256, n0 = blockIdx.x * 256;

  const unsigned short* ga = A + (size_t)(m0 + (tid >> 2)) * K + (tid & 3) * 8;
  const unsigned short* gb = B + (size_t)(n0 + (tid >> 2)) * K + (tid & 3) * 8;
  char* ldsA0 = (char*)&Asl[0][0] + w * 1024;
  char* ldsB0 = (char*)&Bsl[0][0] + w * 1024;

  auto stageA = [&](int h) {
    int slot = h & 3, k0 = h * 32;
    load_lds16(ga + k0, ldsA0 + slot * 16384);
    load_lds16(ga + k0 + (size_t)128 * K, ldsA0 + slot * 16384 + 8192);
  };
  auto stageB = [&](int h) {
    int slot = h & 3, k0 = h * 32;
    load_lds16(gb + k0, ldsB0 + slot * 16384);
    load_lds16(gb + k0 + (size_t)128 * K, ldsB0 + slot * 16384 + 8192);
  };

  f32x4 acc[8][4];
#pragma unroll
  for (int i = 0; i < 8; ++i)
#pragma unroll
    for (int j = 0; j < 4; ++j) acc[i][j] = (f32x4){0.f, 0.f, 0.f, 0.f};

  stageA(0); stageB(0); stageA(1); stageB(1); stageA(2); stageB(2);
  asm volatile("s_waitcnt vmcnt(8)" ::: "memory");
  __builtin_amdgcn_s_barrier();

  for (int h = 0; h < NH; ++h) {
    int slot = h & 3;
    const unsigned short* As_ = &Asl[slot][0];
    const unsigned short* Bs_ = &Bsl[slot][0];
    int arow = wm * 128 + lr;
    int brow = wn * 64 + lr;
    short8 a[8], b[4];
#pragma unroll
    for (int i = 0; i < 4; ++i)
      a[i] = *(const short8*)&As_[(arow + i * 16) * 32 + kg8];
#pragma unroll
    for (int j = 0; j < 4; ++j)
      b[j] = *(const short8*)&Bs_[(brow + j * 16) * 32 + kg8];
    if (h + 3 < NH) stageA(h + 3);
    __builtin_amdgcn_s_barrier();
    __builtin_amdgcn_s_setprio(1);
#pragma unroll
    for (int i = 0; i < 4; ++i)
#pragma unroll
      for (int j = 0; j < 4; ++j)
        acc[i][j] = __builtin_amdgcn_mfma_f32_16x16x32_bf16(a[i], b[j], acc[i][j], 0, 0, 0);
    __builtin_amdgcn_s_setprio(0);
    __builtin_amdgcn_s_barrier();
#pragma unroll
    for (int i = 0; i < 4; ++i)
      a[4 + i] = *(const short8*)&As_[(arow + (4 + i) * 16) * 32 + kg8];
    if (h + 3 < NH) stageB(h + 3);
    __builtin_amdgcn_s_barrier();
    __builtin_amdgcn_s_setprio(1);
#pragma unroll
    for (int i = 0; i < 4; ++i)
#pragma unroll
      for (int j = 0; j < 4; ++j)
        acc[4 + i][j] = __builtin_amdgcn_mfma_f32_16x16x32_bf16(a[4 + i], b[j], acc[4 + i][j], 0, 0, 0);
    __builtin_amdgcn_s_setprio(0);
    if (h < NH - 3)       { asm volatile("s_waitcnt vmcnt(8)" ::: "memory"); }
    else if (h == NH - 3) { asm volatile("s_waitcnt vmcnt(4)" ::: "memory"); }
    else if (h == NH - 2) { asm volatile("s_waitcnt vmcnt(0)" ::: "memory"); }
    __builtin_amdgcn_s_barrier();
  }

  int rbase = m0 + wm * 128 + (lane >> 4) * 4;
  int cbase = n0 + wn * 64 + (lane & 15);
  bool isg = (n0 < 4096);
#pragma unroll
  for (int mf = 0; mf < 8; ++mf) {
#pragma unroll
    for (int nf = 0; nf < 4; ++nf) {
      int col = cbase + nf * 16;
#pragma unroll
      for (int rr = 0; rr < 4; ++rr) {
        int row = rbase + mf * 16 + rr;
        float v = acc[mf][nf][rr];
        if (isg) Gout[(size_t)row * 4096 + col] = v / (1.f + __expf(-v));
        else     Xout[(size_t)row * 4096 + (col - 4096)] = f2bf(v);
      }
    }
  }
}

// ---------------- bf16 MFMA GEMM, 4-slot ring pipeline (T3+T4+T5) ----------------
// MODE 0: plain f32 store (split-K via blockIdx.z); MODE 1: softplus->bf16;
// MODE 2: acc + add (residual)
template<int MODE>
__global__ __launch_bounds__(256)
void gemm_bt(const unsigned short* __restrict__ A,
             const unsigned short* __restrict__ B,
             float* __restrict__ C,
             int M, int N, int K, int ksteps_per_z,
             const float* __restrict__ bias,
             const float* __restrict__ add) {
  __shared__ unsigned short As[4][128 * 32];
  __shared__ unsigned short Bs[4][128 * 32];
  int tid = threadIdx.x;
  int w = tid >> 6, lane = tid & 63;
  int m0 = blockIdx.y * 128, n0 = blockIdx.x * 128;
  int kz0 = blockIdx.z * ksteps_per_z * 32;
  if (MODE == 0) C += (size_t)blockIdx.z * M * N;
  const int NH = ksteps_per_z;

  f32x4 acc[4][4];
#pragma unroll
  for (int i = 0; i < 4; ++i)
#pragma unroll
    for (int j = 0; j < 4; ++j) acc[i][j] = (f32x4){0.f, 0.f, 0.f, 0.f};

  int wm = w >> 1, wn = w & 1;
  int lr = lane & 15, kg = lane >> 4;

  int fe0 = (w) * 512 + lane * 8;
  int fe1 = (4 + w) * 512 + lane * 8;
  int r0 = fe0 >> 5, c0 = fe0 & 31;
  int r1 = fe1 >> 5, c1 = fe1 & 31;
  const unsigned short* Ag0 = A + (size_t)(m0 + r0) * K + c0 + kz0;
  const unsigned short* Ag1 = A + (size_t)(m0 + r1) * K + c1 + kz0;
  const unsigned short* Bg0 = B + (size_t)(n0 + r0) * K + c0 + kz0;
  const unsigned short* Bg1 = B + (size_t)(n0 + r1) * K + c1 + kz0;

  auto stage = [&](int h) {
    int slot = h & 3, kk = h * 32;
    load_lds16(Ag0 + kk, &As[slot][(w) * 512]);
    load_lds16(Ag1 + kk, &As[slot][(4 + w) * 512]);
    load_lds16(Bg0 + kk, &Bs[slot][(w) * 512]);
    load_lds16(Bg1 + kk, &Bs[slot][(4 + w) * 512]);
  };

  stage(0);
  if (NH > 1) stage(1);
  if (NH > 2) stage(2);

  for (int h = 0; h < NH; ++h) {
    int slot = h & 3;
    __builtin_amdgcn_s_barrier();        // all waves done reading slot (h-1)&3
    if (h + 3 < NH) stage(h + 3);        // safe to overwrite it now
    int rem = NH - 1 - h; if (rem > 3) rem = 3;
    if (rem == 3)      { asm volatile("s_waitcnt vmcnt(12)" ::: "memory"); }
    else if (rem == 2) { asm volatile("s_waitcnt vmcnt(8)"  ::: "memory"); }
    else if (rem == 1) { asm volatile("s_waitcnt vmcnt(4)"  ::: "memory"); }
    else               { asm volatile("s_waitcnt vmcnt(0)"  ::: "memory"); }
    __builtin_amdgcn_s_barrier();        // slot h fully landed for all waves
    short8 a[4], b[4];
#pragma unroll
    for (int i = 0; i < 4; ++i)
      a[i] = *(const short8*)&As[slot][(wm * 64 + i * 16 + lr) * 32 + kg * 8];
#pragma unroll
    for (int j = 0; j < 4; ++j)
      b[j] = *(const short8*)&Bs[slot][(wn * 64 + j * 16 + lr) * 32 + kg * 8];
    __builtin_amdgcn_s_setprio(1);
#pragma unroll
    for (int i = 0; i < 4; ++i)
#pragma unroll
      for (int j = 0; j < 4; ++j)
        acc[i][j] = __builtin_amdgcn_mfma_f32_16x16x32_bf16(a[i], b[j], acc[i][j], 0, 0, 0);
    __builtin_amdgcn_s_setprio(0);
  }

#pragma unroll
  for (int i = 0; i < 4; ++i) {
#pragma unroll
    for (int j = 0; j < 4; ++j) {
      int rbase = m0 + wm * 64 + i * 16 + kg * 4;
      int col = n0 + wn * 64 + j * 16 + lr;
#pragma unroll
      for (int r = 0; r < 4; ++r) {
        float v = acc[i][j][r];
        size_t idx = (size_t)(rbase + r) * N + col;
        if (MODE == 0) {
          C[idx] = v;
        } else if (MODE == 1) {
          float t = v + bias[col];
          ((unsigned short*)C)[idx] = f2bf((t > 20.f) ? t : log1pf(__expf(t)));
        } else {
          C[idx] = v + add[idx];
        }
      }
    }
  }
}

// ---------------- depthwise causal conv (K=4) + SiLU -> bf16 ----------------
__global__ void conv_silu_kernel(const unsigned short* __restrict__ xin,
                                 const float* __restrict__ cw,
                                 const float* __restrict__ cb,
                                 unsigned short* __restrict__ xbf) {
  size_t idx = (size_t)blockIdx.x * blockDim.x + threadIdx.x;
  if (idx >= (size_t)NB * NL * NE) return;
  int e = (int)(idx & (NE - 1));
  int r = (int)(idx >> 12);            // b*NL + l
  int l = r & (NL - 1);
  float acc = cb[e];
#pragma unroll
  for (int k = 0; k < NKC; ++k) {
    int ls = l - 3 + k;
    if (ls >= 0) acc += bf2f(xin[(size_t)(r - 3 + k) * NE + e]) * cw[e * 4 + k];
  }
  float s = acc / (1.f + __expf(-acc));
  xbf[idx] = f2bf(s);
}

// ---------------- reduce split-K partials of the concat GEMM ----------------
__global__ void reduce_tcat_kernel(const float* __restrict__ part,
                                   unsigned short* __restrict__ tbf,
                                   float* __restrict__ bc) {
  int idx = blockIdx.x * blockDim.x + threadIdx.x;
  if (idx >= NBL * 160) return;
  int m = idx / 160, c = idx - m * 160;
  float s = 0.f;
#pragma unroll
  for (int z = 0; z < 8; ++z) s += part[(size_t)z * NBL * 256 + (size_t)m * 256 + c];
  if (c < 128) tbf[m * 128 + c] = f2bf(s);
  else if (c < 144) bc[m * 32 + (c - 128)] = s;
  else bc[m * 32 + 16 + (c - 144)] = s;
}

// ======== selective scan, 4-way L-split, SCAN_T=32 (high occupancy) ========
// K1: per-segment local scan. seg0 rows: final gated output; seg>0: ungated
// partial y (bf16). Writes fin[seg][b][e][n], dtot[seg][b][e].
// Staging per chunk (per wave, uniform): w0/w1: dx(1KB)+BC(1KB); w2/w3: g(1KB)+BC(1KB)
// (seg>0 skips g -> w2/w3 issue 1; vmcnt constant is wave-uniform-branched).
__global__ __launch_bounds__(256)
void scan1_kernel(const unsigned short* __restrict__ delta_bf,
                  const unsigned short* __restrict__ x_bf,
                  const float* __restrict__ bc,
                  const float* __restrict__ gf,
                  const float* __restrict__ A_log,
                  const float* __restrict__ W_D,
                  unsigned short* __restrict__ yg,
                  float* __restrict__ fin,
                  float* __restrict__ dtot) {
  __shared__ unsigned short dxl[2][SCAN_T][2][16];  // [buf][t][{d,x}][e]  4KB
  __shared__ float gl[2][SCAN_T][16];               // 4KB
  __shared__ float BCl[2][SCAN_T][32];              // 8KB
  __shared__ float yl2[SCAN_T][16][2];              // 4KB
  __shared__ float wdl[16];
  int tid = threadIdx.x;
  int n = tid & 15, el = tid >> 4;
  int w = tid >> 6, lane = tid & 63;
  int e0 = blockIdx.x * 16;
  int b = blockIdx.y >> 2, seg = blockIdx.y & 3;
  int e = e0 + el;
  float A2 = -__expf(A_log[e * 16 + n]) * 1.44269504f;
  if (tid < 16) wdl[tid] = W_D[e0 + tid];
  float h = 0.f, cum = 0.f;

  const unsigned short* gdl = delta_bf + (size_t)b * NL * NE + e0;
  const unsigned short* gx  = x_bf + (size_t)b * NL * NE + e0;
  const float* gg  = gf + (size_t)b * NL * 4096 + e0;
  const float* gBC = bc + (size_t)b * NL * 32;

  // per-lane source geometry
  const unsigned short* dxsrc = ((lane >> 1) & 1) ? gx : gdl;  // waves 0,1
  int dxrow = (w & 1) * 16 + (lane >> 2);
  int dxcol = (lane & 1) * 8;
  int grow = (w & 1) * 16 + (lane >> 2);                        // waves 2,3
  int gcol = (lane & 3) * 4;
  int bcrow = w * 8 + (lane >> 3);                              // all waves
  int bccol = (lane & 7) * 4;
  int nloads = (seg == 0 || w < 2) ? 2 : 1;

  auto stage = [&](int buf, int c) {
    int l0 = seg * SEG_T + c * SCAN_T;
    if (w < 2)
      load_lds16(dxsrc + (size_t)(l0 + dxrow) * NE + dxcol, &dxl[buf][(w & 1) * 16][0][0]);
    else if (seg == 0)
      load_lds16(gg + (size_t)(l0 + grow) * 4096 + gcol, &gl[buf][(w & 1) * 16][0]);
    load_lds16(gBC + (size_t)(l0 + bcrow) * 32 + bccol, &BCl[buf][w * 8][0]);
  };

  stage(0, 0);
  const int nch = SEG_T / SCAN_T;  // 8
  for (int c = 0; c < nch; ++c) {
    int cur = c & 1;
    if (c + 1 < nch) {
      stage(cur ^ 1, c + 1);
      if (nloads == 2) { asm volatile("s_waitcnt vmcnt(2)" ::: "memory"); }
      else             { asm volatile("s_waitcnt vmcnt(1)" ::: "memory"); }
    } else {
      asm volatile("s_waitcnt vmcnt(0)" ::: "memory");
    }
    __syncthreads();
    const unsigned short (*dxc)[2][16] = dxl[cur];
    const float (*BCc)[32] = BCl[cur];
#pragma unroll 8
    for (int t = 0; t < SCAN_T; ++t) {
      float dc = bf2f(dxc[t][0][el]);
      float xc = bf2f(dxc[t][1][el]);
      float Bc = BCc[t][n];
      float Cc = BCc[t][16 + n];
      cum += dc;
      float a = dc * A2, ed;
      asm("v_exp_f32 %0, %1" : "=v"(ed) : "v"(a));   // exp2(d*A*log2e)
      h = ed * h + (dc * xc) * Bc;
      float p = h * Cc;
      p += dpp_mov<0xB1>(p);    // xor1
      p += dpp_mov<0x4E>(p);    // xor2
      p += dpp_mov<0x141>(p);   // half-mirror -> lanes 0,8 hold 8-group sums
      if ((n & 7) == 0) yl2[t][el][n >> 3] = p;
    }
    __syncthreads();
    {
      int t = tid >> 3, part = tid & 7;   // 2 e's per thread
      int l0 = seg * SEG_T + c * SCAN_T;
      ushort2_t o;
#pragma unroll
      for (int j = 0; j < 2; ++j) {
        int ee = part * 2 + j;
        float xv = bf2f(dxc[t][1][ee]);
        float y = yl2[t][ee][0] + yl2[t][ee][1] + xv * wdl[ee];
        if (seg == 0) y *= gl[cur][t][ee];
        o[j] = f2bf(y);
      }
      *(ushort2_t*)(yg + (size_t)(b * NL + l0 + t) * NE + e0 + part * 2) = o;
    }
    __syncthreads();
  }
  fin[(size_t)((seg * 2 + b) * 4096 + e) * 16 + n] = h;
  if (n == 0) dtot[(size_t)(seg * 2 + b) * 4096 + e] = cum;
}

// K2: fixup for segments 1..3: y_true[t] = y_part[t] + C_t . (exp(A*cumd[t]) (.) h_in),
// then gate. h_in from mini-recurrence over fin/dtot.
// Staging per chunk: w0: d(1KB)+C0; w1: yp(1KB)+C1; w2: g0; w3: g1.
__global__ __launch_bounds__(256)
void scan2_kernel(const unsigned short* __restrict__ delta_bf,
                  unsigned short* __restrict__ yg,
                  const float* __restrict__ bc,
                  const float* __restrict__ gf,
                  const float* __restrict__ A_log,
                  const float* __restrict__ fin,
                  const float* __restrict__ dtot) {
  __shared__ unsigned short dl[2][SCAN_T][16];      // 2KB
  __shared__ unsigned short ypl[2][SCAN_T][16];     // 2KB
  __shared__ float Cl[2][SCAN_T][16];               // 4KB
  __shared__ float gl2[2][SCAN_T][16];              // 4KB
  __shared__ float ycl[SCAN_T][16][2];              // 4KB
  int tid = threadIdx.x;
  int n = tid & 15, el = tid >> 4;
  int w = tid >> 6, lane = tid & 63;
  int e0 = blockIdx.x * 16;
  int b = blockIdx.y / 3, seg = 1 + blockIdx.y % 3;
  int e = e0 + el;
  float A2 = -__expf(A_log[e * 16 + n]) * 1.44269504f;
  // h_in = state entering this segment (recurrence over per-segment locals)
  float h = fin[(size_t)(b * 4096 + e) * 16 + n];           // seg 0 final
  for (int s2 = 1; s2 < seg; ++s2) {
    float dt = dtot[(size_t)(s2 * 2 + b) * 4096 + e];
    float a = A2 * dt, pw;
    asm("v_exp_f32 %0, %1" : "=v"(pw) : "v"(a));
    h = fin[(size_t)((s2 * 2 + b) * 4096 + e) * 16 + n] + pw * h;
  }

  const unsigned short* gd = delta_bf + (size_t)b * NL * NE + e0;
  unsigned short* gy = yg + (size_t)b * NL * NE + e0;
  const float* gg  = gf + (size_t)b * NL * 4096 + e0;
  const float* gBC = bc + (size_t)b * NL * 32;

  int dyrow = lane >> 1;                    // 32 rows, full chunk in one wave-load
  int dycol = (lane & 1) * 8;
  int crow = (w & 1) * 16 + (lane >> 2);    // waves 0,1 (C rows 0-15 / 16-31)
  int ccol = 16 + (lane & 3) * 4;           // C half of bc row
  int grow = (w & 1) * 16 + (lane >> 2);    // waves 2,3
  int gcol = (lane & 3) * 4;
  int nloads = (w < 2) ? 2 : 1;

  auto stage = [&](int buf, int c) {
    int l0 = seg * SEG_T + c * SCAN_T;
    if (w == 0)      load_lds16(gd + (size_t)(l0 + dyrow) * NE + dycol, &dl[buf][0][0]);
    else if (w == 1) load_lds16(gy + (size_t)(l0 + dyrow) * NE + dycol, &ypl[buf][0][0]);
    if (w < 2) load_lds16(gBC + (size_t)(l0 + crow) * 32 + ccol, &Cl[buf][(w & 1) * 16][0]);
    else       load_lds16(gg + (size_t)(l0 + grow) * 4096 + gcol, &gl2[buf][(w & 1) * 16][0]);
  };

  stage(0, 0);
  float cum = 0.f;
  const int nch = SEG_T / SCAN_T;  // 8
  for (int c = 0; c < nch; ++c) {
    int cur = c & 1;
    if (c + 1 < nch) {
      stage(cur ^ 1, c + 1);
      if (nloads == 2) { asm volatile("s_waitcnt vmcnt(2)" ::: "memory"); }
      else             { asm volatile("s_waitcnt vmcnt(1)" ::: "memory"); }
    } else {
      asm volatile("s_waitcnt vmcnt(0)" ::: "memory");
    }
    __syncthreads();
    const unsigned short (*dc_)[16] = dl[cur];
    const float (*Cc_)[16] = Cl[cur];
#pragma unroll 8
    for (int t = 0; t < SCAN_T; ++t) {
      float dcv = bf2f(dc_[t][el]);
      cum += dcv;
      float a = A2 * cum, pw;
      asm("v_exp_f32 %0, %1" : "=v"(pw) : "v"(a));
      float p = (pw * h) * Cc_[t][n];
      p += dpp_mov<0xB1>(p);
      p += dpp_mov<0x4E>(p);
      p += dpp_mov<0x141>(p);
      if ((n & 7) == 0) ycl[t][el][n >> 3] = p;
    }
    __syncthreads();
    {
      int t = tid >> 3, part = tid & 7;   // 2 e's per thread
      int l0 = seg * SEG_T + c * SCAN_T;
      ushort2_t o;
#pragma unroll
      for (int j = 0; j < 2; ++j) {
        int ee = part * 2 + j;
        float y = ycl[t][ee][0] + ycl[t][ee][1] + bf2f(ypl[cur][t][ee]);
        o[j] = f2bf(y * gl2[cur][t][ee]);
      }
      *(ushort2_t*)(gy + (size_t)(l0 + t) * NE + part * 2) = o;
    }
    __syncthreads();
  }
}

// ---------------- host launcher ----------------
extern "C" void kernel_launch(void* const* d_in, const int* in_sizes, int n_in,
                              void* d_out, int out_size, void* d_ws, size_t ws_size,
                              hipStream_t stream) {
  const float* resid  = (const float*)d_in[0];
  const float* norm_w = (const float*)d_in[1];
  const float* skip_w = (const float*)d_in[2];
  const float* in_w   = (const float*)d_in[3];
  const float* conv_w = (const float*)d_in[4];
  const float* conv_b = (const float*)d_in[5];
  const float* wd1    = (const float*)d_in[6];
  const float* wd2    = (const float*)d_in[7];
  const float* wd2_b  = (const float*)d_in[8];
  const float* wB     = (const float*)d_in[9];
  const float* wC     = (const float*)d_in[10];
  const float* A_log  = (const float*)d_in[11];
  const float* W_D    = (const float*)d_in[12];
  const float* out_w  = (const float*)d_in[13];
  float* out = (float*)d_out;

  char* ws = (char*)d_ws;
  size_t off = 0;
  auto alloc = [&](size_t bytes) -> void* {
    void* p = ws + off;
    off += (bytes + 255) & ~(size_t)255;
    return p;
  };
  unsigned short* rn_bf      = (unsigned short*)alloc((size_t)NBL * ND * 2);
  unsigned short* wskipin_bf = (unsigned short*)alloc((size_t)2 * NE * ND * 2);  // [skip_w; in_w]
  unsigned short* wout_bf    = (unsigned short*)alloc((size_t)ND * NE * 2);
  unsigned short* wd2_bf     = (unsigned short*)alloc((size_t)NE * NR * 2);
  unsigned short* wcat_bf    = (unsigned short*)alloc((size_t)256 * NE * 2);
  float* g_f                 = (float*)alloc((size_t)NBL * NE * 4);   // silu(skip)
  unsigned short* xin_bf     = (unsigned short*)alloc((size_t)NBL * NE * 2);
  unsigned short* x_bf       = (unsigned short*)alloc((size_t)NBL * NE * 2);
  float* part_f              = (float*)alloc((size_t)8 * NBL * 256 * 4);
  unsigned short* t_bf       = (unsigned short*)alloc((size_t)NBL * NR * 2);
  float* bc_f                = (float*)alloc((size_t)NBL * 32 * 4);
  unsigned short* yg_bf      = (unsigned short*)alloc((size_t)NBL * NE * 2);
  float* fin_f               = (float*)alloc((size_t)4 * NB * NE * 16 * 4);
  float* dtot_f              = (float*)alloc((size_t)4 * NB * NE * 4);
  // delta (bf16) aliases wskipin_bf: wskipin consumed by fused GEMM (step 3),
  // delta written at step 8 -> stream-ordered, safe, deterministic.
  unsigned short* delta_bf = wskipin_bf;
  (void)ws_size; (void)in_sizes; (void)n_in; (void)out_size;

  // 1. RMSNorm -> rn bf16
  rmsnorm_kernel<<<dim3(NBL), dim3(256), 0, stream>>>(resid, norm_w, rn_bf);

  // 2. weight casts
  cast_bf16_kernel<<<dim3((NE * ND / 8 + 255) / 256), dim3(256), 0, stream>>>(skip_w, wskipin_bf, NE * ND / 8);
  cast_bf16_kernel<<<dim3((NE * ND / 8 + 255) / 256), dim3(256), 0, stream>>>(in_w, wskipin_bf + (size_t)NE * ND, NE * ND / 8);
  cast_bf16_kernel<<<dim3((ND * NE / 8 + 255) / 256), dim3(256), 0, stream>>>(out_w, wout_bf, ND * NE / 8);
  cast_bf16_kernel<<<dim3((NE * NR / 8 + 255) / 256), dim3(256), 0, stream>>>(wd2, wd2_bf, NE * NR / 8);
  build_wcat_kernel<<<dim3(256 * NE / 8 / 256), dim3(256), 0, stream>>>(wd1, wB, wC, wcat_bf);

  // 3. fused [g|xin] = rn @ [skip_w; in_w]^T  (256^2 pipelined kernel)
  gemm256_fused<<<dim3(8192 / 256, NBL / 256), dim3(512), 0, stream>>>(
      rn_bf, wskipin_bf, g_f, xin_bf);

  // 5. conv + silu -> x_bf
  conv_silu_kernel<<<dim3((int)(((size_t)NB * NL * NE) / 256)), dim3(256), 0, stream>>>(
      xin_bf, conv_w, conv_b, x_bf);

  // 6. tcat = x @ [wd1;wB;wC]^T  split-K=8 -> partials
  gemm_bt<0><<<dim3(256 / 128, NBL / 128, 8), dim3(256), 0, stream>>>(
      x_bf, wcat_bf, part_f, NBL, 256, NE, (NE / 32) / 8, nullptr, nullptr);
  // 7. reduce partials -> t_bf, bc (interleaved B|C)
  reduce_tcat_kernel<<<dim3((NBL * 160 + 255) / 256), dim3(256), 0, stream>>>(
      part_f, t_bf, bc_f);

  // 8. delta = softplus(t @ wd2^T + wd2_b) -> bf16  [2048,4096] k=128
  gemm_bt<1><<<dim3(NE / 128, NBL / 128, 1), dim3(256), 0, stream>>>(
      t_bf, wd2_bf, (float*)delta_bf, NBL, NE, NR, NR / 32, wd2_b, nullptr);

  // 9a. segment-local scans (4-way L-split)
  scan1_kernel<<<dim3(NE / 16, NB * 4), dim3(256), 0, stream>>>(
      delta_bf, x_bf, bc_f, g_f, A_log, W_D, yg_bf, fin_f, dtot_f);
  // 9b. fixup segments 1..3 (+ gating)
  scan2_kernel<<<dim3(NE / 16, NB * 3), dim3(256), 0, stream>>>(
      delta_bf, yg_bf, bc_f, g_f, A_log, fin_f, dtot_f);

  // 10. out = resid + yg @ out_w^T   [2048,2048] k=4096
  gemm_bt<2><<<dim3(ND / 128, NBL / 128, 1), dim3(256), 0, stream>>>(
      yg_bf, wout_bf, out, NBL, ND, NE, NE / 32, nullptr, resid);
}

// Round 10
// 411.602 us; speedup vs baseline: 1.1255x; 1.0187x over previous
//
#include <hip/hip_runtime.h>
#include <stdint.h>

// ---- problem constants ----
#define NB 2
#define NL 1024
#define ND 2048
#define NE 4096
#define NN 16
#define NR 128
#define NKC 4
#define NBL (NB*NL)          // 2048 rows
#define EPSV 1e-5f
#define SEG_T 256            // scan L-split segment length (4 segments)
#define SCAN_T 32            // LDS chunk within a segment (small -> high occupancy)

typedef __attribute__((ext_vector_type(4))) float f32x4;
typedef __attribute__((ext_vector_type(8))) short short8;
typedef __attribute__((ext_vector_type(8))) unsigned short ushort8;
typedef __attribute__((ext_vector_type(4))) unsigned short ushort4_t;
typedef __attribute__((ext_vector_type(2))) unsigned short ushort2_t;

__device__ __forceinline__ unsigned short f2bf(float f) {
  union { float f; unsigned u; } v; v.f = f;
  unsigned r = v.u + 0x7FFFu + ((v.u >> 16) & 1u);   // RNE
  return (unsigned short)(r >> 16);
}

__device__ __forceinline__ float bf2f(unsigned short u) {
  union { unsigned u; float f; } v; v.u = (unsigned)u << 16; return v.f;
}

__device__ __forceinline__ void load_lds16(const void* g, void* l) {
  __builtin_amdgcn_global_load_lds((const __attribute__((address_space(1))) void*)g,
                                   (__attribute__((address_space(3))) void*)l,
                                   16, 0, 0);
}

template<int CTRL>
__device__ __forceinline__ float dpp_mov(float v) {
  return __int_as_float(__builtin_amdgcn_update_dpp(
      0, __float_as_int(v), CTRL, 0xF, 0xF, true));
}

// ---------------- RMSNorm: resid[row,0:2048] -> rn_bf16 ----------------
__global__ void rmsnorm_kernel(const float* __restrict__ resid,
                               const float* __restrict__ nw,
                               unsigned short* __restrict__ rn) {
  int row = blockIdx.x;
  int tid = threadIdx.x;                 // 256 threads, 8 f32 each
  const float* r = resid + (size_t)row * ND;
  f32x4 v0 = *(const f32x4*)(r + tid * 8);
  f32x4 v1 = *(const f32x4*)(r + tid * 8 + 4);
  float vals[8];
#pragma unroll
  for (int i = 0; i < 4; ++i) { vals[i] = v0[i]; vals[4 + i] = v1[i]; }
  float ss = 0.f;
#pragma unroll
  for (int i = 0; i < 8; ++i) ss += vals[i] * vals[i];
  for (int o = 32; o > 0; o >>= 1) ss += __shfl_down(ss, o);
  __shared__ float ps[4];
  if ((tid & 63) == 0) ps[tid >> 6] = ss;
  __syncthreads();
  float tot = ps[0] + ps[1] + ps[2] + ps[3];
  float scale = rsqrtf(tot / (float)ND + EPSV);
  ushort8 o8;
#pragma unroll
  for (int i = 0; i < 8; ++i) o8[i] = f2bf(vals[i] * scale * nw[tid * 8 + i]);
  *(ushort8*)(rn + (size_t)row * ND + tid * 8) = o8;
}

// ---------------- generic f32 -> bf16 cast (8 elems/thread) ----------------
__global__ void cast_bf16_kernel(const float* __restrict__ in,
                                 unsigned short* __restrict__ out, int n8) {
  int i = blockIdx.x * blockDim.x + threadIdx.x;
  if (i >= n8) return;
  f32x4 a = *(const f32x4*)(in + (size_t)i * 8);
  f32x4 b = *(const f32x4*)(in + (size_t)i * 8 + 4);
  ushort8 o;
#pragma unroll
  for (int j = 0; j < 4; ++j) { o[j] = f2bf(a[j]); o[4 + j] = f2bf(b[j]); }
  *(ushort8*)(out + (size_t)i * 8) = o;
}

// ---- build concatenated [256 x 4096] bf16 weight: rows 0-127 wd1, 128-143 wB, 144-159 wC, rest 0
__global__ void build_wcat_kernel(const float* __restrict__ wd1,
                                  const float* __restrict__ wB,
                                  const float* __restrict__ wC,
                                  unsigned short* __restrict__ out) {
  int i = blockIdx.x * blockDim.x + threadIdx.x;   // total 256*4096/8 = 131072
  if (i >= 256 * NE / 8) return;
  int col8 = i & (NE / 8 - 1);
  int row = i >> 9;
  const float* src = nullptr; int srow = 0;
  if (row < 128)      { src = wd1; srow = row; }
  else if (row < 144) { src = wB;  srow = row - 128; }
  else if (row < 160) { src = wC;  srow = row - 144; }
  ushort8 o;
  if (src) {
    f32x4 a = *(const f32x4*)(src + (size_t)srow * NE + col8 * 8);
    f32x4 b = *(const f32x4*)(src + (size_t)srow * NE + col8 * 8 + 4);
#pragma unroll
    for (int j = 0; j < 4; ++j) { o[j] = f2bf(a[j]); o[4 + j] = f2bf(b[j]); }
  } else {
#pragma unroll
    for (int j = 0; j < 8; ++j) o[j] = 0;
  }
  *(ushort8*)(out + (size_t)row * NE + col8 * 8) = o;
}

// ======== 256x256 multi-phase counted-vmcnt GEMM (fused skip+in proj) ========
__global__ __launch_bounds__(512, 2)
void gemm256_fused(const unsigned short* __restrict__ A,
                   const unsigned short* __restrict__ B,
                   float* __restrict__ Gout,
                   unsigned short* __restrict__ Xout) {
  const int K = 2048, NH = K / 32;   // 64 K-halves
  __shared__ unsigned short Asl[4][8192];   // [slot][r*32+c]  r<256, c<32
  __shared__ unsigned short Bsl[4][8192];
  int tid = threadIdx.x;
  int w = tid >> 6, lane = tid & 63;
  int wm = w >> 2, wn = w & 3;
  int lr = lane & 15, kg8 = (lane >> 4) * 8;
  int m0 = blockIdx.y * 256, n0 = blockIdx.x * 256;

  const unsigned short* ga = A + (size_t)(m0 + (tid >> 2)) * K + (tid & 3) * 8;
  const unsigned short* gb = B + (size_t)(n0 + (tid >> 2)) * K + (tid & 3) * 8;
  char* ldsA0 = (char*)&Asl[0][0] + w * 1024;
  char* ldsB0 = (char*)&Bsl[0][0] + w * 1024;

  auto stageA = [&](int h) {
    int slot = h & 3, k0 = h * 32;
    load_lds16(ga + k0, ldsA0 + slot * 16384);
    load_lds16(ga + k0 + (size_t)128 * K, ldsA0 + slot * 16384 + 8192);
  };
  auto stageB = [&](int h) {
    int slot = h & 3, k0 = h * 32;
    load_lds16(gb + k0, ldsB0 + slot * 16384);
    load_lds16(gb + k0 + (size_t)128 * K, ldsB0 + slot * 16384 + 8192);
  };

  f32x4 acc[8][4];
#pragma unroll
  for (int i = 0; i < 8; ++i)
#pragma unroll
    for (int j = 0; j < 4; ++j) acc[i][j] = (f32x4){0.f, 0.f, 0.f, 0.f};

  stageA(0); stageB(0); stageA(1); stageB(1); stageA(2); stageB(2);
  asm volatile("s_waitcnt vmcnt(8)" ::: "memory");
  __builtin_amdgcn_s_barrier();

  for (int h = 0; h < NH; ++h) {
    int slot = h & 3;
    const unsigned short* As_ = &Asl[slot][0];
    const unsigned short* Bs_ = &Bsl[slot][0];
    int arow = wm * 128 + lr;
    int brow = wn * 64 + lr;
    short8 a[8], b[4];
#pragma unroll
    for (int i = 0; i < 4; ++i)
      a[i] = *(const short8*)&As_[(arow + i * 16) * 32 + kg8];
#pragma unroll
    for (int j = 0; j < 4; ++j)
      b[j] = *(const short8*)&Bs_[(brow + j * 16) * 32 + kg8];
    if (h + 3 < NH) stageA(h + 3);
    __builtin_amdgcn_s_barrier();
    __builtin_amdgcn_s_setprio(1);
#pragma unroll
    for (int i = 0; i < 4; ++i)
#pragma unroll
      for (int j = 0; j < 4; ++j)
        acc[i][j] = __builtin_amdgcn_mfma_f32_16x16x32_bf16(a[i], b[j], acc[i][j], 0, 0, 0);
    __builtin_amdgcn_s_setprio(0);
    __builtin_amdgcn_s_barrier();
#pragma unroll
    for (int i = 0; i < 4; ++i)
      a[4 + i] = *(const short8*)&As_[(arow + (4 + i) * 16) * 32 + kg8];
    if (h + 3 < NH) stageB(h + 3);
    __builtin_amdgcn_s_barrier();
    __builtin_amdgcn_s_setprio(1);
#pragma unroll
    for (int i = 0; i < 4; ++i)
#pragma unroll
      for (int j = 0; j < 4; ++j)
        acc[4 + i][j] = __builtin_amdgcn_mfma_f32_16x16x32_bf16(a[4 + i], b[j], acc[4 + i][j], 0, 0, 0);
    __builtin_amdgcn_s_setprio(0);
    if (h < NH - 3)       { asm volatile("s_waitcnt vmcnt(8)" ::: "memory"); }
    else if (h == NH - 3) { asm volatile("s_waitcnt vmcnt(4)" ::: "memory"); }
    else if (h == NH - 2) { asm volatile("s_waitcnt vmcnt(0)" ::: "memory"); }
    __builtin_amdgcn_s_barrier();
  }

  int rbase = m0 + wm * 128 + (lane >> 4) * 4;
  int cbase = n0 + wn * 64 + (lane & 15);
  bool isg = (n0 < 4096);
#pragma unroll
  for (int mf = 0; mf < 8; ++mf) {
#pragma unroll
    for (int nf = 0; nf < 4; ++nf) {
      int col = cbase + nf * 16;
#pragma unroll
      for (int rr = 0; rr < 4; ++rr) {
        int row = rbase + mf * 16 + rr;
        float v = acc[mf][nf][rr];
        if (isg) Gout[(size_t)row * 4096 + col] = v / (1.f + __expf(-v));
        else     Xout[(size_t)row * 4096 + (col - 4096)] = f2bf(v);
      }
    }
  }
}

// ---------------- bf16 MFMA GEMM, 3-slot ring pipeline (T3+T4+T5) ----------------
// C[M,N] = A[M,K] @ B[N,K]^T. 128x128 tile, 256 threads (4 waves 2x2), BK=32.
// 3-slot ring (48KB LDS -> 3 blocks/CU): stage h+2 during h, counted vmcnt(8),
// raw s_barrier only. MODE 0: f32 partials (split-K via z); MODE 1: softplus->bf16.
template<int MODE>
__global__ __launch_bounds__(256)
void gemm_bt(const unsigned short* __restrict__ A,
             const unsigned short* __restrict__ B,
             float* __restrict__ C,
             int M, int N, int K, int ksteps_per_z,
             const float* __restrict__ bias) {
  __shared__ unsigned short As[3][128 * 32];
  __shared__ unsigned short Bs[3][128 * 32];
  int tid = threadIdx.x;
  int w = tid >> 6, lane = tid & 63;
  int m0 = blockIdx.y * 128, n0 = blockIdx.x * 128;
  int kz0 = blockIdx.z * ksteps_per_z * 32;
  if (MODE == 0) C += (size_t)blockIdx.z * M * N;
  const int NH = ksteps_per_z;

  f32x4 acc[4][4];
#pragma unroll
  for (int i = 0; i < 4; ++i)
#pragma unroll
    for (int j = 0; j < 4; ++j) acc[i][j] = (f32x4){0.f, 0.f, 0.f, 0.f};

  int wm = w >> 1, wn = w & 1;
  int lr = lane & 15, kg = lane >> 4;

  int fe0 = (w) * 512 + lane * 8;
  int fe1 = (4 + w) * 512 + lane * 8;
  int r0 = fe0 >> 5, c0 = fe0 & 31;
  int r1 = fe1 >> 5, c1 = fe1 & 31;
  const unsigned short* Ag0 = A + (size_t)(m0 + r0) * K + c0 + kz0;
  const unsigned short* Ag1 = A + (size_t)(m0 + r1) * K + c1 + kz0;
  const unsigned short* Bg0 = B + (size_t)(n0 + r0) * K + c0 + kz0;
  const unsigned short* Bg1 = B + (size_t)(n0 + r1) * K + c1 + kz0;

  auto stage = [&](int h) {
    int slot = h % 3, kk = h * 32;
    load_lds16(Ag0 + kk, &As[slot][(w) * 512]);
    load_lds16(Ag1 + kk, &As[slot][(4 + w) * 512]);
    load_lds16(Bg0 + kk, &Bs[slot][(w) * 512]);
    load_lds16(Bg1 + kk, &Bs[slot][(4 + w) * 512]);
  };

  // prologue: 2 slots in flight
  stage(0);
  if (NH > 1) stage(1);

  for (int h = 0; h < NH; ++h) {
    int slot = h % 3;
    __builtin_amdgcn_s_barrier();        // all waves done reading slot (h-1)%3
    if (h + 2 < NH) stage(h + 2);        // overwrite it now
    int rem = NH - 1 - h;
    if (rem >= 2)      { asm volatile("s_waitcnt vmcnt(8)" ::: "memory"); }
    else if (rem == 1) { asm volatile("s_waitcnt vmcnt(4)" ::: "memory"); }
    else               { asm volatile("s_waitcnt vmcnt(0)" ::: "memory"); }
    __builtin_amdgcn_s_barrier();        // slot h fully landed for all waves
    short8 a[4], b[4];
#pragma unroll
    for (int i = 0; i < 4; ++i)
      a[i] = *(const short8*)&As[slot][(wm * 64 + i * 16 + lr) * 32 + kg * 8];
#pragma unroll
    for (int j = 0; j < 4; ++j)
      b[j] = *(const short8*)&Bs[slot][(wn * 64 + j * 16 + lr) * 32 + kg * 8];
    __builtin_amdgcn_s_setprio(1);
#pragma unroll
    for (int i = 0; i < 4; ++i)
#pragma unroll
      for (int j = 0; j < 4; ++j)
        acc[i][j] = __builtin_amdgcn_mfma_f32_16x16x32_bf16(a[i], b[j], acc[i][j], 0, 0, 0);
    __builtin_amdgcn_s_setprio(0);
  }

  // epilogue: C/D layout col=lane&15, row=(lane>>4)*4+reg  (verified m89/m91)
#pragma unroll
  for (int i = 0; i < 4; ++i) {
#pragma unroll
    for (int j = 0; j < 4; ++j) {
      int rbase = m0 + wm * 64 + i * 16 + kg * 4;
      int col = n0 + wn * 64 + j * 16 + lr;
#pragma unroll
      for (int r = 0; r < 4; ++r) {
        float v = acc[i][j][r];
        size_t idx = (size_t)(rbase + r) * N + col;
        if (MODE == 0) {
          C[idx] = v;
        } else {
          float t = v + bias[col];
          ((unsigned short*)C)[idx] = f2bf((t > 20.f) ? t : log1pf(__expf(t)));
        }
      }
    }
  }
}

// ---------------- out reduction: out = resid + sum_z part[z] ----------------
__global__ void reduce_out_kernel(const float* __restrict__ part,
                                  const float* __restrict__ resid,
                                  float* __restrict__ out) {
  size_t base = ((size_t)blockIdx.x * blockDim.x + threadIdx.x) * 4;
  if (base >= (size_t)NBL * ND) return;
  f32x4 r = *(const f32x4*)(resid + base);
#pragma unroll
  for (int z = 0; z < 4; ++z)
    r += *(const f32x4*)(part + (size_t)z * NBL * ND + base);
  *(f32x4*)(out + base) = r;
}

// ---------------- depthwise causal conv (K=4) + SiLU -> bf16 ----------------
__global__ void conv_silu_kernel(const unsigned short* __restrict__ xin,
                                 const float* __restrict__ cw,
                                 const float* __restrict__ cb,
                                 unsigned short* __restrict__ xbf) {
  size_t idx = (size_t)blockIdx.x * blockDim.x + threadIdx.x;
  if (idx >= (size_t)NB * NL * NE) return;
  int e = (int)(idx & (NE - 1));
  int r = (int)(idx >> 12);            // b*NL + l
  int l = r & (NL - 1);
  float acc = cb[e];
#pragma unroll
  for (int k = 0; k < NKC; ++k) {
    int ls = l - 3 + k;
    if (ls >= 0) acc += bf2f(xin[(size_t)(r - 3 + k) * NE + e]) * cw[e * 4 + k];
  }
  float s = acc / (1.f + __expf(-acc));
  xbf[idx] = f2bf(s);
}

// ---------------- reduce split-K partials of the concat GEMM (16 slices) ----------------
__global__ void reduce_tcat_kernel(const float* __restrict__ part,
                                   unsigned short* __restrict__ tbf,
                                   float* __restrict__ bc) {
  int idx = blockIdx.x * blockDim.x + threadIdx.x;
  if (idx >= NBL * 160) return;
  int m = idx / 160, c = idx - m * 160;
  float s = 0.f;
#pragma unroll
  for (int z = 0; z < 16; ++z) s += part[(size_t)z * NBL * 256 + (size_t)m * 256 + c];
  if (c < 128) tbf[m * 128 + c] = f2bf(s);
  else if (c < 144) bc[m * 32 + (c - 128)] = s;
  else bc[m * 32 + 16 + (c - 144)] = s;
}

// ======== selective scan, 4-way L-split, SCAN_T=32 (high occupancy) ========
__global__ __launch_bounds__(256)
void scan1_kernel(const unsigned short* __restrict__ delta_bf,
                  const unsigned short* __restrict__ x_bf,
                  const float* __restrict__ bc,
                  const float* __restrict__ gf,
                  const float* __restrict__ A_log,
                  const float* __restrict__ W_D,
                  unsigned short* __restrict__ yg,
                  float* __restrict__ fin,
                  float* __restrict__ dtot) {
  __shared__ unsigned short dxl[2][SCAN_T][2][16];  // [buf][t][{d,x}][e]  4KB
  __shared__ float gl[2][SCAN_T][16];               // 4KB
  __shared__ float BCl[2][SCAN_T][32];              // 8KB
  __shared__ float yl2[SCAN_T][16][2];              // 4KB
  __shared__ float wdl[16];
  int tid = threadIdx.x;
  int n = tid & 15, el = tid >> 4;
  int w = tid >> 6, lane = tid & 63;
  int e0 = blockIdx.x * 16;
  int b = blockIdx.y >> 2, seg = blockIdx.y & 3;
  int e = e0 + el;
  float A2 = -__expf(A_log[e * 16 + n]) * 1.44269504f;
  if (tid < 16) wdl[tid] = W_D[e0 + tid];
  float h = 0.f, cum = 0.f;

  const unsigned short* gdl = delta_bf + (size_t)b * NL * NE + e0;
  const unsigned short* gx  = x_bf + (size_t)b * NL * NE + e0;
  const float* gg  = gf + (size_t)b * NL * 4096 + e0;
  const float* gBC = bc + (size_t)b * NL * 32;

  const unsigned short* dxsrc = ((lane >> 1) & 1) ? gx : gdl;  // waves 0,1
  int dxrow = (w & 1) * 16 + (lane >> 2);
  int dxcol = (lane & 1) * 8;
  int grow = (w & 1) * 16 + (lane >> 2);                        // waves 2,3
  int gcol = (lane & 3) * 4;
  int bcrow = w * 8 + (lane >> 3);                              // all waves
  int bccol = (lane & 7) * 4;
  int nloads = (seg == 0 || w < 2) ? 2 : 1;

  auto stage = [&](int buf, int c) {
    int l0 = seg * SEG_T + c * SCAN_T;
    if (w < 2)
      load_lds16(dxsrc + (size_t)(l0 + dxrow) * NE + dxcol, &dxl[buf][(w & 1) * 16][0][0]);
    else if (seg == 0)
      load_lds16(gg + (size_t)(l0 + grow) * 4096 + gcol, &gl[buf][(w & 1) * 16][0]);
    load_lds16(gBC + (size_t)(l0 + bcrow) * 32 + bccol, &BCl[buf][w * 8][0]);
  };

  stage(0, 0);
  const int nch = SEG_T / SCAN_T;  // 8
  for (int c = 0; c < nch; ++c) {
    int cur = c & 1;
    if (c + 1 < nch) {
      stage(cur ^ 1, c + 1);
      if (nloads == 2) { asm volatile("s_waitcnt vmcnt(2)" ::: "memory"); }
      else             { asm volatile("s_waitcnt vmcnt(1)" ::: "memory"); }
    } else {
      asm volatile("s_waitcnt vmcnt(0)" ::: "memory");
    }
    __syncthreads();
    const unsigned short (*dxc)[2][16] = dxl[cur];
    const float (*BCc)[32] = BCl[cur];
#pragma unroll 8
    for (int t = 0; t < SCAN_T; ++t) {
      float dc = bf2f(dxc[t][0][el]);
      float xc = bf2f(dxc[t][1][el]);
      float Bc = BCc[t][n];
      float Cc = BCc[t][16 + n];
      cum += dc;
      float a = dc * A2, ed;
      asm("v_exp_f32 %0, %1" : "=v"(ed) : "v"(a));   // exp2(d*A*log2e)
      h = ed * h + (dc * xc) * Bc;
      float p = h * Cc;
      p += dpp_mov<0xB1>(p);    // xor1
      p += dpp_mov<0x4E>(p);    // xor2
      p += dpp_mov<0x141>(p);   // half-mirror -> lanes 0,8 hold 8-group sums
      if ((n & 7) == 0) yl2[t][el][n >> 3] = p;
    }
    __syncthreads();
    {
      int t = tid >> 3, part = tid & 7;   // 2 e's per thread
      int l0 = seg * SEG_T + c * SCAN_T;
      ushort2_t o;
#pragma unroll
      for (int j = 0; j < 2; ++j) {
        int ee = part * 2 + j;
        float xv = bf2f(dxc[t][1][ee]);
        float y = yl2[t][ee][0] + yl2[t][ee][1] + xv * wdl[ee];
        if (seg == 0) y *= gl[cur][t][ee];
        o[j] = f2bf(y);
      }
      *(ushort2_t*)(yg + (size_t)(b * NL + l0 + t) * NE + e0 + part * 2) = o;
    }
    __syncthreads();
  }
  fin[(size_t)((seg * 2 + b) * 4096 + e) * 16 + n] = h;
  if (n == 0) dtot[(size_t)(seg * 2 + b) * 4096 + e] = cum;
}

// K2: fixup for segments 1..3
__global__ __launch_bounds__(256)
void scan2_kernel(const unsigned short* __restrict__ delta_bf,
                  unsigned short* __restrict__ yg,
                  const float* __restrict__ bc,
                  const float* __restrict__ gf,
                  const float* __restrict__ A_log,
                  const float* __restrict__ fin,
                  const float* __restrict__ dtot) {
  __shared__ unsigned short dl[2][SCAN_T][16];      // 2KB
  __shared__ unsigned short ypl[2][SCAN_T][16];     // 2KB
  __shared__ float Cl[2][SCAN_T][16];               // 4KB
  __shared__ float gl2[2][SCAN_T][16];              // 4KB
  __shared__ float ycl[SCAN_T][16][2];              // 4KB
  int tid = threadIdx.x;
  int n = tid & 15, el = tid >> 4;
  int w = tid >> 6, lane = tid & 63;
  int e0 = blockIdx.x * 16;
  int b = blockIdx.y / 3, seg = 1 + blockIdx.y % 3;
  int e = e0 + el;
  float A2 = -__expf(A_log[e * 16 + n]) * 1.44269504f;
  float h = fin[(size_t)(b * 4096 + e) * 16 + n];           // seg 0 final
  for (int s2 = 1; s2 < seg; ++s2) {
    float dt = dtot[(size_t)(s2 * 2 + b) * 4096 + e];
    float a = A2 * dt, pw;
    asm("v_exp_f32 %0, %1" : "=v"(pw) : "v"(a));
    h = fin[(size_t)((s2 * 2 + b) * 4096 + e) * 16 + n] + pw * h;
  }

  const unsigned short* gd = delta_bf + (size_t)b * NL * NE + e0;
  unsigned short* gy = yg + (size_t)b * NL * NE + e0;
  const float* gg  = gf + (size_t)b * NL * 4096 + e0;
  const float* gBC = bc + (size_t)b * NL * 32;

  int dyrow = lane >> 1;
  int dycol = (lane & 1) * 8;
  int crow = (w & 1) * 16 + (lane >> 2);
  int ccol = 16 + (lane & 3) * 4;
  int grow = (w & 1) * 16 + (lane >> 2);
  int gcol = (lane & 3) * 4;
  int nloads = (w < 2) ? 2 : 1;

  auto stage = [&](int buf, int c) {
    int l0 = seg * SEG_T + c * SCAN_T;
    if (w == 0)      load_lds16(gd + (size_t)(l0 + dyrow) * NE + dycol, &dl[buf][0][0]);
    else if (w == 1) load_lds16(gy + (size_t)(l0 + dyrow) * NE + dycol, &ypl[buf][0][0]);
    if (w < 2) load_lds16(gBC + (size_t)(l0 + crow) * 32 + ccol, &Cl[buf][(w & 1) * 16][0]);
    else       load_lds16(gg + (size_t)(l0 + grow) * 4096 + gcol, &gl2[buf][(w & 1) * 16][0]);
  };

  stage(0, 0);
  float cum = 0.f;
  const int nch = SEG_T / SCAN_T;  // 8
  for (int c = 0; c < nch; ++c) {
    int cur = c & 1;
    if (c + 1 < nch) {
      stage(cur ^ 1, c + 1);
      if (nloads == 2) { asm volatile("s_waitcnt vmcnt(2)" ::: "memory"); }
      else             { asm volatile("s_waitcnt vmcnt(1)" ::: "memory"); }
    } else {
      asm volatile("s_waitcnt vmcnt(0)" ::: "memory");
    }
    __syncthreads();
    const unsigned short (*dc_)[16] = dl[cur];
    const float (*Cc_)[16] = Cl[cur];
#pragma unroll 8
    for (int t = 0; t < SCAN_T; ++t) {
      float dcv = bf2f(dc_[t][el]);
      cum += dcv;
      float a = A2 * cum, pw;
      asm("v_exp_f32 %0, %1" : "=v"(pw) : "v"(a));
      float p = (pw * h) * Cc_[t][n];
      p += dpp_mov<0xB1>(p);
      p += dpp_mov<0x4E>(p);
      p += dpp_mov<0x141>(p);
      if ((n & 7) == 0) ycl[t][el][n >> 3] = p;
    }
    __syncthreads();
    {
      int t = tid >> 3, part = tid & 7;
      int l0 = seg * SEG_T + c * SCAN_T;
      ushort2_t o;
#pragma unroll
      for (int j = 0; j < 2; ++j) {
        int ee = part * 2 + j;
        float y = ycl[t][ee][0] + ycl[t][ee][1] + bf2f(ypl[cur][t][ee]);
        o[j] = f2bf(y * gl2[cur][t][ee]);
      }
      *(ushort2_t*)(gy + (size_t)(l0 + t) * NE + part * 2) = o;
    }
    __syncthreads();
  }
}

// ---------------- host launcher ----------------
extern "C" void kernel_launch(void* const* d_in, const int* in_sizes, int n_in,
                              void* d_out, int out_size, void* d_ws, size_t ws_size,
                              hipStream_t stream) {
  const float* resid  = (const float*)d_in[0];
  const float* norm_w = (const float*)d_in[1];
  const float* skip_w = (const float*)d_in[2];
  const float* in_w   = (const float*)d_in[3];
  const float* conv_w = (const float*)d_in[4];
  const float* conv_b = (const float*)d_in[5];
  const float* wd1    = (const float*)d_in[6];
  const float* wd2    = (const float*)d_in[7];
  const float* wd2_b  = (const float*)d_in[8];
  const float* wB     = (const float*)d_in[9];
  const float* wC     = (const float*)d_in[10];
  const float* A_log  = (const float*)d_in[11];
  const float* W_D    = (const float*)d_in[12];
  const float* out_w  = (const float*)d_in[13];
  float* out = (float*)d_out;

  char* ws = (char*)d_ws;
  size_t off = 0;
  auto alloc = [&](size_t bytes) -> void* {
    void* p = ws + off;
    off += (bytes + 255) & ~(size_t)255;
    return p;
  };
  unsigned short* rn_bf      = (unsigned short*)alloc((size_t)NBL * ND * 2);
  unsigned short* wskipin_bf = (unsigned short*)alloc((size_t)2 * NE * ND * 2);  // [skip_w; in_w]
  unsigned short* wout_bf    = (unsigned short*)alloc((size_t)ND * NE * 2);
  unsigned short* wd2_bf     = (unsigned short*)alloc((size_t)NE * NR * 2);
  unsigned short* wcat_bf    = (unsigned short*)alloc((size_t)256 * NE * 2);
  float* g_f                 = (float*)alloc((size_t)NBL * NE * 4);   // silu(skip)  33.55MB
  unsigned short* xin_bf     = (unsigned short*)alloc((size_t)NBL * NE * 2);  // 16.78MB
  unsigned short* x_bf       = (unsigned short*)alloc((size_t)NBL * NE * 2);  // 16.78MB
  float* part_f              = (float*)alloc((size_t)16 * NBL * 256 * 4);
  unsigned short* t_bf       = (unsigned short*)alloc((size_t)NBL * NR * 2);
  float* bc_f                = (float*)alloc((size_t)NBL * 32 * 4);
  unsigned short* yg_bf      = (unsigned short*)alloc((size_t)NBL * NE * 2);
  float* fin_f               = (float*)alloc((size_t)4 * NB * NE * 16 * 4);
  float* dtot_f              = (float*)alloc((size_t)4 * NB * NE * 4);
  // delta (bf16) aliases wskipin_bf (consumed by step 3, rewritten each replay).
  unsigned short* delta_bf = wskipin_bf;
  // out-GEMM split-K partials (4 x 16.78MB = 67.1MB) alias g_f+xin_bf+x_bf
  // (exactly 67.1MB contiguous, all dead after scan2 -> stream-ordered safe).
  float* part2_f = g_f;
  (void)ws_size; (void)in_sizes; (void)n_in; (void)out_size;

  // 1. RMSNorm -> rn bf16
  rmsnorm_kernel<<<dim3(NBL), dim3(256), 0, stream>>>(resid, norm_w, rn_bf);

  // 2. weight casts
  cast_bf16_kernel<<<dim3((NE * ND / 8 + 255) / 256), dim3(256), 0, stream>>>(skip_w, wskipin_bf, NE * ND / 8);
  cast_bf16_kernel<<<dim3((NE * ND / 8 + 255) / 256), dim3(256), 0, stream>>>(in_w, wskipin_bf + (size_t)NE * ND, NE * ND / 8);
  cast_bf16_kernel<<<dim3((ND * NE / 8 + 255) / 256), dim3(256), 0, stream>>>(out_w, wout_bf, ND * NE / 8);
  cast_bf16_kernel<<<dim3((NE * NR / 8 + 255) / 256), dim3(256), 0, stream>>>(wd2, wd2_bf, NE * NR / 8);
  build_wcat_kernel<<<dim3(256 * NE / 8 / 256), dim3(256), 0, stream>>>(wd1, wB, wC, wcat_bf);

  // 3. fused [g|xin] = rn @ [skip_w; in_w]^T  (256^2 pipelined kernel)
  gemm256_fused<<<dim3(8192 / 256, NBL / 256), dim3(512), 0, stream>>>(
      rn_bf, wskipin_bf, g_f, xin_bf);

  // 5. conv + silu -> x_bf
  conv_silu_kernel<<<dim3((int)(((size_t)NB * NL * NE) / 256)), dim3(256), 0, stream>>>(
      xin_bf, conv_w, conv_b, x_bf);

  // 6. tcat = x @ [wd1;wB;wC]^T  split-K=16 -> partials
  gemm_bt<0><<<dim3(256 / 128, NBL / 128, 16), dim3(256), 0, stream>>>(
      x_bf, wcat_bf, part_f, NBL, 256, NE, (NE / 32) / 16, nullptr);
  // 7. reduce partials -> t_bf, bc (interleaved B|C)
  reduce_tcat_kernel<<<dim3((NBL * 160 + 255) / 256), dim3(256), 0, stream>>>(
      part_f, t_bf, bc_f);

  // 8. delta = softplus(t @ wd2^T + wd2_b) -> bf16  [2048,4096] k=128
  gemm_bt<1><<<dim3(NE / 128, NBL / 128, 1), dim3(256), 0, stream>>>(
      t_bf, wd2_bf, (float*)delta_bf, NBL, NE, NR, NR / 32, wd2_b);

  // 9a. segment-local scans (4-way L-split)
  scan1_kernel<<<dim3(NE / 16, NB * 4), dim3(256), 0, stream>>>(
      delta_bf, x_bf, bc_f, g_f, A_log, W_D, yg_bf, fin_f, dtot_f);
  // 9b. fixup segments 1..3 (+ gating)
  scan2_kernel<<<dim3(NE / 16, NB * 3), dim3(256), 0, stream>>>(
      delta_bf, yg_bf, bc_f, g_f, A_log, fin_f, dtot_f);

  // 10a. out partials = yg @ out_w^T  split-K=4  [2048,2048] k=1024 each
  gemm_bt<0><<<dim3(ND / 128, NBL / 128, 4), dim3(256), 0, stream>>>(
      yg_bf, wout_bf, part2_f, NBL, ND, NE, (NE / 32) / 4, nullptr);
  // 10b. out = resid + sum partials
  reduce_out_kernel<<<dim3((int)((size_t)NBL * ND / 4 / 256)), dim3(256), 0, stream>>>(
      part2_f, resid, out);
}